// Round 1
// baseline (2691.871 us; speedup 1.0000x reference)
//
#include <hip/hip_runtime.h>
#include <math.h>

#define N_NODES 20000
#define E_EDGES 320000
#define EP (E_EDGES + N_NODES)   // 340000 edges incl. self-loops
#define D 256
#define NHEAD 4
#define CH 64
#define NEG_SLOPE 0.2f
#define LN_EPS 1e-5f

// ---------- helpers ----------
__device__ __forceinline__ void atomicMaxFloat(float* addr, float v) {
    // works for mixed signs given init = -inf
    if (v >= 0.0f) atomicMax(reinterpret_cast<int*>(addr), __float_as_int(v));
    else           atomicMin(reinterpret_cast<unsigned int*>(addr), __float_as_uint(v));
}

// ---------- GEMM: X = A(nrows x 256) @ W(256 x 256), two weight mats ----------
// grid (ceil(nrows/64), 4, 2), block 256. z selects (W0->X0) or (W1->X1).
__global__ __launch_bounds__(256)
void gemm_dual(const float* __restrict__ A,
               const float* __restrict__ W0, const float* __restrict__ W1,
               float* __restrict__ X0, float* __restrict__ X1, int nrows)
{
    const float* W = (blockIdx.z == 0) ? W0 : W1;
    float*       X = (blockIdx.z == 0) ? X0 : X1;

    __shared__ float As[16][65];  // [k][m]
    __shared__ float Bs[16][65];  // [k][n]

    const int row0 = blockIdx.x * 64;
    const int col0 = blockIdx.y * 64;
    const int tid  = threadIdx.x;
    const int tx   = tid & 15;   // col group (4 cols each)
    const int ty   = tid >> 4;   // row group (4 rows each)

    float acc[4][4] = {};

    for (int k0 = 0; k0 < 256; k0 += 16) {
        // load A tile 64x16 (1024 elems, 4 per thread)
        #pragma unroll
        for (int i = 0; i < 4; ++i) {
            int e = tid + i * 256;
            int r = e >> 4, k = e & 15;
            int grow = row0 + r;
            float v = (grow < nrows) ? A[grow * 256 + k0 + k] : 0.0f;
            As[k][r] = v;
        }
        // load W tile 16x64 (coalesced along cols)
        #pragma unroll
        for (int i = 0; i < 4; ++i) {
            int e = tid + i * 256;
            int k = e >> 6, c = e & 63;
            Bs[k][c] = W[(k0 + k) * 256 + col0 + c];
        }
        __syncthreads();
        #pragma unroll
        for (int k = 0; k < 16; ++k) {
            float a[4], b[4];
            #pragma unroll
            for (int i = 0; i < 4; ++i) a[i] = As[k][ty * 4 + i];
            #pragma unroll
            for (int j = 0; j < 4; ++j) b[j] = Bs[k][tx * 4 + j];
            #pragma unroll
            for (int i = 0; i < 4; ++i)
                #pragma unroll
                for (int j = 0; j < 4; ++j) acc[i][j] += a[i] * b[j];
        }
        __syncthreads();
    }
    #pragma unroll
    for (int i = 0; i < 4; ++i) {
        int grow = row0 + ty * 4 + i;
        if (grow < nrows) {
            #pragma unroll
            for (int j = 0; j < 4; ++j)
                X[grow * 256 + col0 + tx * 4 + j] = acc[i][j];
        }
    }
}

// ---------- init: agg = bias (broadcast), m = -inf, denom = 0 ----------
__global__ __launch_bounds__(256)
void init_layer(float* __restrict__ agg, const float* __restrict__ bias,
                float* __restrict__ m, float* __restrict__ denom)
{
    int i = blockIdx.x * 256 + threadIdx.x;
    if (i < N_NODES * D) agg[i] = bias[i & 255];
    if (i < N_NODES * NHEAD) { m[i] = -INFINITY; denom[i] = 0.0f; }
}

// ---------- scores: s[e,h] = sum_c leaky(xl[src]+xr[dst]) * att ; atomicMax m ----------
__global__ __launch_bounds__(256)
void scores_kernel(const float* __restrict__ xl, const float* __restrict__ xr,
                   const int* __restrict__ ei, const float* __restrict__ att,
                   float* __restrict__ s, float* __restrict__ m)
{
    int t = blockIdx.x * 256 + threadIdx.x;
    if (t >= EP * NHEAD) return;
    int e = t >> 2;
    int h = t & 3;
    int src, dst;
    if (e < E_EDGES) { src = ei[e]; dst = ei[E_EDGES + e]; }
    else             { src = dst = e - E_EDGES; }

    const float4* pl = reinterpret_cast<const float4*>(xl + src * D + h * CH);
    const float4* pr = reinterpret_cast<const float4*>(xr + dst * D + h * CH);
    const float4* pa = reinterpret_cast<const float4*>(att + h * CH);
    float acc = 0.0f;
    #pragma unroll
    for (int i = 0; i < 16; ++i) {
        float4 a = pl[i], b = pr[i], w = pa[i];
        float v;
        v = a.x + b.x; acc += ((v > 0.0f) ? v : v * NEG_SLOPE) * w.x;
        v = a.y + b.y; acc += ((v > 0.0f) ? v : v * NEG_SLOPE) * w.y;
        v = a.z + b.z; acc += ((v > 0.0f) ? v : v * NEG_SLOPE) * w.z;
        v = a.w + b.w; acc += ((v > 0.0f) ? v : v * NEG_SLOPE) * w.w;
    }
    s[t] = acc;
    atomicMaxFloat(&m[dst * NHEAD + h], acc);
}

// ---------- exp + denom ----------
__global__ __launch_bounds__(256)
void expsum_kernel(const int* __restrict__ ei, float* __restrict__ s,
                   const float* __restrict__ m, float* __restrict__ denom)
{
    int t = blockIdx.x * 256 + threadIdx.x;
    if (t >= EP * NHEAD) return;
    int e = t >> 2;
    int h = t & 3;
    int dst = (e < E_EDGES) ? ei[E_EDGES + e] : (e - E_EDGES);
    float v = expf(s[t] - m[dst * NHEAD + h]);
    s[t] = v;  // s now holds exp-numerator
    atomicAdd(&denom[dst * NHEAD + h], v);
}

// ---------- aggregation: agg[dst, j] += alpha(e, h(j)) * xl[src, j] ----------
// one block (256 threads) per edge
__global__ __launch_bounds__(256)
void aggregate_kernel(const float* __restrict__ xl, const int* __restrict__ ei,
                      const float* __restrict__ s, const float* __restrict__ denom,
                      float* __restrict__ agg)
{
    int e = blockIdx.x;
    int j = threadIdx.x;
    int src, dst;
    if (e < E_EDGES) { src = ei[e]; dst = ei[E_EDGES + e]; }
    else             { src = dst = e - E_EDGES; }
    int h = j >> 6;
    float alpha = s[e * NHEAD + h] / denom[dst * NHEAD + h];
    atomicAdd(&agg[dst * D + j], alpha * xl[src * D + j]);
}

// ---------- layernorm + relu (one wave per node, 4 nodes/block) ----------
__global__ __launch_bounds__(256)
void ln_relu_kernel(const float* __restrict__ in, const float* __restrict__ g,
                    const float* __restrict__ be, float* __restrict__ out)
{
    int wave = threadIdx.x >> 6;
    int lane = threadIdx.x & 63;
    int n = blockIdx.x * 4 + wave;
    if (n >= N_NODES) return;

    float4 v = reinterpret_cast<const float4*>(in + n * D)[lane];
    float sum = v.x + v.y + v.z + v.w;
    #pragma unroll
    for (int o = 1; o < 64; o <<= 1) sum += __shfl_xor(sum, o, 64);
    float mu = sum * (1.0f / 256.0f);

    float4 d = make_float4(v.x - mu, v.y - mu, v.z - mu, v.w - mu);
    float ss = d.x * d.x + d.y * d.y + d.z * d.z + d.w * d.w;
    #pragma unroll
    for (int o = 1; o < 64; o <<= 1) ss += __shfl_xor(ss, o, 64);
    float rstd = rsqrtf(ss * (1.0f / 256.0f) + LN_EPS);

    float4 gg = reinterpret_cast<const float4*>(g)[lane];
    float4 bb = reinterpret_cast<const float4*>(be)[lane];
    float4 o4;
    o4.x = fmaxf(d.x * rstd * gg.x + bb.x, 0.0f);
    o4.y = fmaxf(d.y * rstd * gg.y + bb.y, 0.0f);
    o4.z = fmaxf(d.z * rstd * gg.z + bb.z, 0.0f);
    o4.w = fmaxf(d.w * rstd * gg.w + bb.w, 0.0f);
    reinterpret_cast<float4*>(out + n * D)[lane] = o4;
}

// ---------- launch ----------
extern "C" void kernel_launch(void* const* d_in, const int* in_sizes, int n_in,
                              void* d_out, int out_size, void* d_ws, size_t ws_size,
                              hipStream_t stream)
{
    const float* x  = (const float*)d_in[0];
    const int*   ei = (const int*)d_in[1];

    float* ws = (float*)d_ws;
    float* buf_h  = ws;                 // N*D   (agg accumulator / hidden state)
    float* buf_xl = ws + 5120000;       // N*D
    float* buf_xr = ws + 10240000;      // N*D
    float* sbuf   = ws + 15360000;      // EP*NHEAD
    float* mbuf   = ws + 16720000;      // N*NHEAD
    float* dbuf   = ws + 16800000;      // N*NHEAD

    const int threads = 256;
    dim3 gemm_grid(313, 4, 2);                       // ceil(20000/64)=313
    int init_blocks  = (N_NODES * D + 255) / 256;    // 20000
    int eh_blocks    = (EP * NHEAD + 255) / 256;     // 5313
    int ln_blocks    = N_NODES / 4;                  // 5000

    for (int l = 0; l < 4; ++l) {
        const float* Wl   = (const float*)d_in[2 + 6 * l + 0];
        const float* Wr   = (const float*)d_in[2 + 6 * l + 1];
        const float* att  = (const float*)d_in[2 + 6 * l + 2];
        const float* bias = (const float*)d_in[2 + 6 * l + 3];
        const float* g    = (const float*)d_in[2 + 6 * l + 4];
        const float* be   = (const float*)d_in[2 + 6 * l + 5];

        const float* A = (l == 0) ? x : buf_h;
        gemm_dual<<<gemm_grid, threads, 0, stream>>>(A, Wl, Wr, buf_xl, buf_xr, N_NODES);
        init_layer<<<init_blocks, threads, 0, stream>>>(buf_h, bias, mbuf, dbuf);
        scores_kernel<<<eh_blocks, threads, 0, stream>>>(buf_xl, buf_xr, ei, att, sbuf, mbuf);
        expsum_kernel<<<eh_blocks, threads, 0, stream>>>(ei, sbuf, mbuf, dbuf);
        aggregate_kernel<<<EP, threads, 0, stream>>>(buf_xl, ei, sbuf, dbuf, buf_h);

        float* outp = (l == 3) ? (float*)d_out : buf_h;
        ln_relu_kernel<<<ln_blocks, threads, 0, stream>>>(buf_h, g, be, outp);
    }
}

// Round 2
// 1566.684 us; speedup vs baseline: 1.7182x; 1.7182x over previous
//
#include <hip/hip_runtime.h>
#include <math.h>

#define N_NODES 20000
#define E_EDGES 320000
#define EP (E_EDGES + N_NODES)   // 340000 edges incl. self-loops
#define D 256
#define NHEAD 4
#define CH 64
#define NEG_SLOPE 0.2f
#define LN_EPS 1e-5f

typedef _Float16 half8_t __attribute__((ext_vector_type(8)));
typedef _Float16 half4_t __attribute__((ext_vector_type(4)));
typedef float   float4_t __attribute__((ext_vector_type(4)));

// ================= one-time: convert x (fp32) -> f16 =================
__global__ __launch_bounds__(256)
void convert_x_kernel(const float* __restrict__ x, _Float16* __restrict__ h16)
{
    int i = blockIdx.x * 256 + threadIdx.x;          // one float4 per thread
    if (i >= N_NODES * D / 4) return;
    float4 v = reinterpret_cast<const float4*>(x)[i];
    half4_t o;
    o.x = (_Float16)v.x; o.y = (_Float16)v.y; o.z = (_Float16)v.z; o.w = (_Float16)v.w;
    reinterpret_cast<half4_t*>(h16)[i] = o;
}

// ================= CSR build =================
__global__ __launch_bounds__(256)
void csr_zero_kernel(int* __restrict__ deg)
{
    int i = blockIdx.x * 256 + threadIdx.x;
    if (i < N_NODES) deg[i] = 0;
}

__global__ __launch_bounds__(256)
void csr_hist_kernel(const int* __restrict__ ei, int* __restrict__ deg)
{
    int e = blockIdx.x * 256 + threadIdx.x;
    if (e >= EP) return;
    int dst = (e < E_EDGES) ? ei[E_EDGES + e] : (e - E_EDGES);
    atomicAdd(&deg[dst], 1);
}

__global__ __launch_bounds__(1024)
void csr_scan_kernel(const int* __restrict__ deg, int* __restrict__ rowptr,
                     int* __restrict__ cursor)
{
    __shared__ int wsum[16];
    __shared__ int carry;
    int t = threadIdx.x, lane = t & 63, w = t >> 6;
    if (t == 0) carry = 0;
    __syncthreads();
    for (int base = 0; base < N_NODES; base += 1024) {
        int i = base + t;
        int v = (i < N_NODES) ? deg[i] : 0;
        int x = v;
        #pragma unroll
        for (int o = 1; o < 64; o <<= 1) {
            int y = __shfl_up(x, o, 64);
            if (lane >= o) x += y;
        }
        if (lane == 63) wsum[w] = x;
        __syncthreads();
        if (t == 0) {
            int s = carry;
            #pragma unroll
            for (int k = 0; k < 16; ++k) { int tmp = wsum[k]; wsum[k] = s; s += tmp; }
            carry = s;
        }
        __syncthreads();
        int excl = wsum[w] + x - v;
        if (i < N_NODES) { rowptr[i] = excl; cursor[i] = excl; }
        __syncthreads();
    }
    if (t == 0) rowptr[N_NODES] = carry;
}

__global__ __launch_bounds__(256)
void csr_scatter_kernel(const int* __restrict__ ei, int* __restrict__ cursor,
                        int* __restrict__ csr_src, int* __restrict__ csr_eid)
{
    int e = blockIdx.x * 256 + threadIdx.x;
    if (e >= EP) return;
    int src, dst;
    if (e < E_EDGES) { src = ei[e]; dst = ei[E_EDGES + e]; }
    else             { src = dst = e - E_EDGES; }
    int pos = atomicAdd(&cursor[dst], 1);
    csr_src[pos] = src;
    csr_eid[pos] = e;
}

// ================= per-layer: W convert + transpose to f16 [n][k] =================
// grid (4,4,2), block 256
__global__ __launch_bounds__(256)
void convw_kernel(const float* __restrict__ Wl, const float* __restrict__ Wr,
                  _Float16* __restrict__ Wt)
{
    __shared__ float tile[64][65];
    const float* W = blockIdx.z ? Wr : Wl;
    _Float16* out = Wt + blockIdx.z * 65536;
    int bx = blockIdx.x * 64, by = blockIdx.y * 64;
    int t = threadIdx.x;
    #pragma unroll
    for (int i = 0; i < 16; ++i) {
        int idx = t + i * 256;
        int kk = idx >> 6, nn = idx & 63;
        tile[kk][nn] = W[(by + kk) * 256 + bx + nn];
    }
    __syncthreads();
    #pragma unroll
    for (int i = 0; i < 16; ++i) {
        int idx = t + i * 256;
        int nn = idx >> 6, kk = idx & 63;
        out[(bx + nn) * 256 + by + kk] = (_Float16)tile[kk][nn];
    }
}

// ================= GEMM: X = A16 @ W (f16 MFMA, fp32 accum) =================
// A16: [M][256] f16 row-major; Wt: [2][256][256] f16 laid out [n][k]
// grid (157, 4, 2), block 256 (4 waves). BM=128, BN=64, BK=32.
#define BM 128
#define BN 64
#define BK 32
__global__ __launch_bounds__(256)
void gemm_f16_kernel(const _Float16* __restrict__ A16, const _Float16* __restrict__ Wt,
                     float* __restrict__ X0, float* __restrict__ X1, int nrows)
{
    const _Float16* W = Wt + blockIdx.z * 65536;
    float* X = blockIdx.z ? X1 : X0;
    const int row0 = blockIdx.x * BM;
    const int col0 = blockIdx.y * BN;

    __shared__ _Float16 As[BM][BK + 8];   // pad 8 f16: row stride 80B, 16B-aligned
    __shared__ _Float16 Bs[BN][BK + 8];

    const int tid  = threadIdx.x;
    const int wave = tid >> 6, lane = tid & 63;
    const int quad = lane >> 4, l16 = lane & 15;

    float4_t acc[2][4];
    #pragma unroll
    for (int i = 0; i < 2; ++i)
        #pragma unroll
        for (int j = 0; j < 4; ++j) acc[i][j] = (float4_t)0.0f;

    for (int k0 = 0; k0 < 256; k0 += BK) {
        // stage A: 128x32 f16 -> 2x 16B loads/thread
        #pragma unroll
        for (int i = 0; i < 2; ++i) {
            int idx = tid + i * 256;
            int r = idx >> 2, kk = (idx & 3) * 8;
            int gr = row0 + r;
            half8_t v = (half8_t)(_Float16)0.0f;
            if (gr < nrows)
                v = *reinterpret_cast<const half8_t*>(A16 + gr * 256 + k0 + kk);
            *reinterpret_cast<half8_t*>(&As[r][kk]) = v;
        }
        // stage B: 64x32 f16 -> 1x 16B load/thread
        {
            int r = tid >> 2, kk = (tid & 3) * 8;
            half8_t v = *reinterpret_cast<const half8_t*>(W + (col0 + r) * 256 + k0 + kk);
            *reinterpret_cast<half8_t*>(&Bs[r][kk]) = v;
        }
        __syncthreads();

        half8_t af[2], bf[4];
        #pragma unroll
        for (int i = 0; i < 2; ++i)
            af[i] = *reinterpret_cast<const half8_t*>(&As[wave * 32 + i * 16 + l16][quad * 8]);
        #pragma unroll
        for (int j = 0; j < 4; ++j)
            bf[j] = *reinterpret_cast<const half8_t*>(&Bs[j * 16 + l16][quad * 8]);
        #pragma unroll
        for (int i = 0; i < 2; ++i)
            #pragma unroll
            for (int j = 0; j < 4; ++j)
                acc[i][j] = __builtin_amdgcn_mfma_f32_16x16x32_f16(af[i], bf[j], acc[i][j], 0, 0, 0);
        __syncthreads();
    }
    // epilogue: D[row=quad*4+r][col=l16] per 16x16 tile
    #pragma unroll
    for (int i = 0; i < 2; ++i) {
        #pragma unroll
        for (int r = 0; r < 4; ++r) {
            int gr = row0 + wave * 32 + i * 16 + quad * 4 + r;
            if (gr < nrows) {
                #pragma unroll
                for (int j = 0; j < 4; ++j)
                    X[gr * 256 + col0 + j * 16 + l16] = acc[i][j][r];
            }
        }
    }
}

// ================= scores: s[e,h] = sum_c leaky(xl[src]+xr[dst]) * att =================
__global__ __launch_bounds__(256)
void scores_kernel(const float* __restrict__ xl, const float* __restrict__ xr,
                   const int* __restrict__ ei, const float* __restrict__ att,
                   float* __restrict__ s)
{
    int t = blockIdx.x * 256 + threadIdx.x;
    if (t >= EP * NHEAD) return;
    int e = t >> 2;
    int h = t & 3;
    int src, dst;
    if (e < E_EDGES) { src = ei[e]; dst = ei[E_EDGES + e]; }
    else             { src = dst = e - E_EDGES; }

    const float4* pl = reinterpret_cast<const float4*>(xl + src * D + h * CH);
    const float4* pr = reinterpret_cast<const float4*>(xr + dst * D + h * CH);
    const float4* pa = reinterpret_cast<const float4*>(att + h * CH);
    float acc = 0.0f;
    #pragma unroll
    for (int i = 0; i < 16; ++i) {
        float4 a = pl[i], b = pr[i], w = pa[i];
        float v;
        v = a.x + b.x; acc += ((v > 0.0f) ? v : v * NEG_SLOPE) * w.x;
        v = a.y + b.y; acc += ((v > 0.0f) ? v : v * NEG_SLOPE) * w.y;
        v = a.z + b.z; acc += ((v > 0.0f) ? v : v * NEG_SLOPE) * w.z;
        v = a.w + b.w; acc += ((v > 0.0f) ? v : v * NEG_SLOPE) * w.w;
    }
    s[t] = acc;
}

// ================= softmax stats: one wave per (node, head) =================
__global__ __launch_bounds__(256)
void stats_kernel(const float* __restrict__ s, const int* __restrict__ rowptr,
                  const int* __restrict__ csr_eid,
                  float* __restrict__ mbuf, float* __restrict__ invd)
{
    int wave = threadIdx.x >> 6, lane = threadIdx.x & 63;
    int id = blockIdx.x * 4 + wave;      // 80000 wave-jobs
    int n = id >> 2, h = id & 3;
    int start = rowptr[n], end = rowptr[n + 1];

    float m = -INFINITY;
    for (int i = start + lane; i < end; i += 64)
        m = fmaxf(m, s[csr_eid[i] * 4 + h]);
    #pragma unroll
    for (int o = 1; o < 64; o <<= 1) m = fmaxf(m, __shfl_xor(m, o, 64));

    float d = 0.0f;
    for (int i = start + lane; i < end; i += 64)
        d += __expf(s[csr_eid[i] * 4 + h] - m);
    #pragma unroll
    for (int o = 1; o < 64; o <<= 1) d += __shfl_xor(d, o, 64);

    if (lane == 0) { mbuf[n * 4 + h] = m; invd[n * 4 + h] = 1.0f / d; }
}

// ================= alpha: s[e,h] <- exp(s - m[dst,h]) * invd[dst,h] =================
__global__ __launch_bounds__(256)
void alpha_kernel(const int* __restrict__ ei, float* __restrict__ s,
                  const float* __restrict__ mbuf, const float* __restrict__ invd)
{
    int t = blockIdx.x * 256 + threadIdx.x;
    if (t >= EP * NHEAD) return;
    int e = t >> 2, h = t & 3;
    int dst = (e < E_EDGES) ? ei[E_EDGES + e] : (e - E_EDGES);
    s[t] = __expf(s[t] - mbuf[dst * 4 + h]) * invd[dst * 4 + h];
}

// ================= fused aggregate + LayerNorm + ReLU, one block per node =================
__global__ __launch_bounds__(256)
void agg_ln_kernel(const float* __restrict__ xl, const float* __restrict__ s,
                   const int* __restrict__ rowptr, const int* __restrict__ csr_src,
                   const int* __restrict__ csr_eid,
                   const float* __restrict__ bias, const float* __restrict__ g,
                   const float* __restrict__ be,
                   float* __restrict__ out32, _Float16* __restrict__ out16,
                   int write32)
{
    int n = blockIdx.x;
    int tid = threadIdx.x;
    int h = tid >> 6, lane = tid & 63;
    int start = rowptr[n], end = rowptr[n + 1];

    float acc = bias[tid];
    for (int i = start; i < end; ++i) {
        int src = csr_src[i];          // uniform -> scalar load
        float alpha = s[csr_eid[i] * 4 + h];
        acc += alpha * xl[src * 256 + tid];
    }

    // LayerNorm over the 256 channels of this block
    __shared__ float red[8];
    float wsum = acc, wsq = acc * acc;
    #pragma unroll
    for (int o = 1; o < 64; o <<= 1) {
        wsum += __shfl_xor(wsum, o, 64);
        wsq  += __shfl_xor(wsq,  o, 64);
    }
    if (lane == 0) { red[h] = wsum; red[4 + h] = wsq; }
    __syncthreads();
    float tot  = red[0] + red[1] + red[2] + red[3];
    float tot2 = red[4] + red[5] + red[6] + red[7];
    float mu = tot * (1.0f / 256.0f);
    float var = tot2 * (1.0f / 256.0f) - mu * mu;
    float rstd = rsqrtf(var + LN_EPS);

    float o = fmaxf((acc - mu) * rstd * g[tid] + be[tid], 0.0f);
    if (write32) out32[n * 256 + tid] = o;
    else         out16[n * 256 + tid] = (_Float16)o;
}

// ================= launch =================
extern "C" void kernel_launch(void* const* d_in, const int* in_sizes, int n_in,
                              void* d_out, int out_size, void* d_ws, size_t ws_size,
                              hipStream_t stream)
{
    const float* x  = (const float*)d_in[0];
    const int*   ei = (const int*)d_in[1];

    char* ws = (char*)d_ws;
    size_t off = 0;
    _Float16* h16   = (_Float16*)(ws + off); off += (size_t)N_NODES * D * 2;      // 10.24 MB
    float* xl       = (float*)(ws + off);    off += (size_t)N_NODES * D * 4;      // 20.48 MB
    float* xr       = (float*)(ws + off);    off += (size_t)N_NODES * D * 4;      // 20.48 MB
    float* sbuf     = (float*)(ws + off);    off += (size_t)EP * NHEAD * 4;       // 5.44 MB
    float* mbuf     = (float*)(ws + off);    off += (size_t)N_NODES * NHEAD * 4;
    float* invd     = (float*)(ws + off);    off += (size_t)N_NODES * NHEAD * 4;
    _Float16* Wt    = (_Float16*)(ws + off); off += (size_t)2 * 256 * 256 * 2;
    int* rowptr     = (int*)(ws + off);      off += (size_t)(N_NODES + 32) * 4;
    int* cursor     = (int*)(ws + off);      off += (size_t)N_NODES * 4;
    int* csr_src    = (int*)(ws + off);      off += (size_t)EP * 4;
    int* csr_eid    = (int*)(ws + off);      off += (size_t)EP * 4;

    // one-time per call
    convert_x_kernel<<<(N_NODES * D / 4 + 255) / 256, 256, 0, stream>>>(x, h16);
    csr_zero_kernel<<<(N_NODES + 255) / 256, 256, 0, stream>>>(cursor);          // cursor as deg
    csr_hist_kernel<<<(EP + 255) / 256, 256, 0, stream>>>(ei, cursor);
    csr_scan_kernel<<<1, 1024, 0, stream>>>(cursor, rowptr, cursor);
    csr_scatter_kernel<<<(EP + 255) / 256, 256, 0, stream>>>(ei, cursor, csr_src, csr_eid);

    dim3 gemm_grid((N_NODES + BM - 1) / BM, 256 / BN, 2);   // (157, 4, 2)
    int eh_blocks = (EP * NHEAD + 255) / 256;               // 5313

    for (int l = 0; l < 4; ++l) {
        const float* Wl   = (const float*)d_in[2 + 6 * l + 0];
        const float* Wr   = (const float*)d_in[2 + 6 * l + 1];
        const float* att  = (const float*)d_in[2 + 6 * l + 2];
        const float* bias = (const float*)d_in[2 + 6 * l + 3];
        const float* g    = (const float*)d_in[2 + 6 * l + 4];
        const float* be   = (const float*)d_in[2 + 6 * l + 5];

        convw_kernel<<<dim3(4, 4, 2), 256, 0, stream>>>(Wl, Wr, Wt);
        gemm_f16_kernel<<<gemm_grid, 256, 0, stream>>>(h16, Wt, xl, xr, N_NODES);
        scores_kernel<<<eh_blocks, 256, 0, stream>>>(xl, xr, ei, att, sbuf);
        stats_kernel<<<N_NODES, 256, 0, stream>>>(sbuf, rowptr, csr_eid, mbuf, invd);
        alpha_kernel<<<eh_blocks, 256, 0, stream>>>(ei, sbuf, mbuf, invd);
        agg_ln_kernel<<<N_NODES, 256, 0, stream>>>(xl, sbuf, rowptr, csr_src, csr_eid,
                                                   bias, g, be,
                                                   (float*)d_out, h16, (l == 3) ? 1 : 0);
    }
}

// Round 3
// 665.256 us; speedup vs baseline: 4.0464x; 2.3550x over previous
//
#include <hip/hip_runtime.h>
#include <math.h>

#define N_NODES 20000
#define E_EDGES 320000
#define EP (E_EDGES + N_NODES)   // 340000 edges incl. self-loops
#define D 256
#define NHEAD 4
#define CH 64
#define NEG_SLOPE 0.2f
#define LN_EPS 1e-5f

typedef _Float16 half8_t __attribute__((ext_vector_type(8)));
typedef _Float16 half4_t __attribute__((ext_vector_type(4)));
typedef float   float4_t __attribute__((ext_vector_type(4)));

// ================= one-time: convert x (fp32) -> f16 =================
__global__ __launch_bounds__(256)
void convert_x_kernel(const float* __restrict__ x, _Float16* __restrict__ h16)
{
    int i = blockIdx.x * 256 + threadIdx.x;          // one float4 per thread
    if (i >= N_NODES * D / 4) return;
    float4 v = reinterpret_cast<const float4*>(x)[i];
    half4_t o;
    o.x = (_Float16)v.x; o.y = (_Float16)v.y; o.z = (_Float16)v.z; o.w = (_Float16)v.w;
    reinterpret_cast<half4_t*>(h16)[i] = o;
}

// ================= CSR build =================
__global__ __launch_bounds__(256)
void csr_zero_kernel(int* __restrict__ deg)
{
    int i = blockIdx.x * 256 + threadIdx.x;
    if (i < N_NODES) deg[i] = 0;
}

__global__ __launch_bounds__(256)
void csr_hist_kernel(const int* __restrict__ ei, int* __restrict__ deg)
{
    int e = blockIdx.x * 256 + threadIdx.x;
    if (e >= EP) return;
    int dst = (e < E_EDGES) ? ei[E_EDGES + e] : (e - E_EDGES);
    atomicAdd(&deg[dst], 1);
}

__global__ __launch_bounds__(1024)
void csr_scan_kernel(const int* __restrict__ deg, int* __restrict__ rowptr,
                     int* __restrict__ cursor)
{
    __shared__ int wsum[16];
    __shared__ int carry;
    int t = threadIdx.x, lane = t & 63, w = t >> 6;
    if (t == 0) carry = 0;
    __syncthreads();
    for (int base = 0; base < N_NODES; base += 1024) {
        int i = base + t;
        int v = (i < N_NODES) ? deg[i] : 0;
        int x = v;
        #pragma unroll
        for (int o = 1; o < 64; o <<= 1) {
            int y = __shfl_up(x, o, 64);
            if (lane >= o) x += y;
        }
        if (lane == 63) wsum[w] = x;
        __syncthreads();
        if (t == 0) {
            int s = carry;
            #pragma unroll
            for (int k = 0; k < 16; ++k) { int tmp = wsum[k]; wsum[k] = s; s += tmp; }
            carry = s;
        }
        __syncthreads();
        int excl = wsum[w] + x - v;
        if (i < N_NODES) { rowptr[i] = excl; cursor[i] = excl; }
        __syncthreads();
    }
    if (t == 0) rowptr[N_NODES] = carry;
}

__global__ __launch_bounds__(256)
void csr_scatter_kernel(const int* __restrict__ ei, int* __restrict__ cursor,
                        int* __restrict__ csr_src)
{
    int e = blockIdx.x * 256 + threadIdx.x;
    if (e >= EP) return;
    int src, dst;
    if (e < E_EDGES) { src = ei[e]; dst = ei[E_EDGES + e]; }
    else             { src = dst = e - E_EDGES; }
    int pos = atomicAdd(&cursor[dst], 1);
    csr_src[pos] = src;
}

// ================= per-layer: W convert + transpose to f16 [n][k] =================
// grid (4,4,2), block 256
__global__ __launch_bounds__(256)
void convw_kernel(const float* __restrict__ Wl, const float* __restrict__ Wr,
                  _Float16* __restrict__ Wt)
{
    __shared__ float tile[64][65];
    const float* W = blockIdx.z ? Wr : Wl;
    _Float16* out = Wt + blockIdx.z * 65536;
    int bx = blockIdx.x * 64, by = blockIdx.y * 64;
    int t = threadIdx.x;
    #pragma unroll
    for (int i = 0; i < 16; ++i) {
        int idx = t + i * 256;
        int kk = idx >> 6, nn = idx & 63;
        tile[kk][nn] = W[(by + kk) * 256 + bx + nn];
    }
    __syncthreads();
    #pragma unroll
    for (int i = 0; i < 16; ++i) {
        int idx = t + i * 256;
        int nn = idx >> 6, kk = idx & 63;
        out[(bx + nn) * 256 + by + kk] = (_Float16)tile[kk][nn];
    }
}

// ================= GEMM: X = A16 @ W (f16 MFMA, fp32 accum, f16 out) =================
// A16: [M][256] f16 row-major; Wt: [2][256][256] f16 laid out [n][k]
// grid (157, 4, 2), block 256 (4 waves). BM=128, BN=64, BK=32.
#define BM 128
#define BN 64
#define BK 32
__global__ __launch_bounds__(256)
void gemm_f16_kernel(const _Float16* __restrict__ A16, const _Float16* __restrict__ Wt,
                     _Float16* __restrict__ X0, _Float16* __restrict__ X1, int nrows)
{
    const _Float16* W = Wt + blockIdx.z * 65536;
    _Float16* X = blockIdx.z ? X1 : X0;
    const int row0 = blockIdx.x * BM;
    const int col0 = blockIdx.y * BN;

    __shared__ _Float16 As[BM][BK + 8];   // pad 8 f16: row stride 80B, 16B-aligned
    __shared__ _Float16 Bs[BN][BK + 8];

    const int tid  = threadIdx.x;
    const int wave = tid >> 6, lane = tid & 63;
    const int quad = lane >> 4, l16 = lane & 15;

    float4_t acc[2][4];
    #pragma unroll
    for (int i = 0; i < 2; ++i)
        #pragma unroll
        for (int j = 0; j < 4; ++j) acc[i][j] = (float4_t)0.0f;

    for (int k0 = 0; k0 < 256; k0 += BK) {
        // stage A: 128x32 f16 -> 2x 16B loads/thread
        #pragma unroll
        for (int i = 0; i < 2; ++i) {
            int idx = tid + i * 256;
            int r = idx >> 2, kk = (idx & 3) * 8;
            int gr = row0 + r;
            half8_t v = (half8_t)(_Float16)0.0f;
            if (gr < nrows)
                v = *reinterpret_cast<const half8_t*>(A16 + gr * 256 + k0 + kk);
            *reinterpret_cast<half8_t*>(&As[r][kk]) = v;
        }
        // stage B: 64x32 f16 -> 1x 16B load/thread
        {
            int r = tid >> 2, kk = (tid & 3) * 8;
            half8_t v = *reinterpret_cast<const half8_t*>(W + (col0 + r) * 256 + k0 + kk);
            *reinterpret_cast<half8_t*>(&Bs[r][kk]) = v;
        }
        __syncthreads();

        half8_t af[2], bf[4];
        #pragma unroll
        for (int i = 0; i < 2; ++i)
            af[i] = *reinterpret_cast<const half8_t*>(&As[wave * 32 + i * 16 + l16][quad * 8]);
        #pragma unroll
        for (int j = 0; j < 4; ++j)
            bf[j] = *reinterpret_cast<const half8_t*>(&Bs[j * 16 + l16][quad * 8]);
        #pragma unroll
        for (int i = 0; i < 2; ++i)
            #pragma unroll
            for (int j = 0; j < 4; ++j)
                acc[i][j] = __builtin_amdgcn_mfma_f32_16x16x32_f16(af[i], bf[j], acc[i][j], 0, 0, 0);
        __syncthreads();
    }
    // epilogue: D[row=quad*4+r][col=l16] per 16x16 tile
    #pragma unroll
    for (int i = 0; i < 2; ++i) {
        #pragma unroll
        for (int r = 0; r < 4; ++r) {
            int gr = row0 + wave * 32 + i * 16 + quad * 4 + r;
            if (gr < nrows) {
                #pragma unroll
                for (int j = 0; j < 4; ++j)
                    X[gr * 256 + col0 + j * 16 + l16] = (_Float16)acc[i][j][r];
            }
        }
    }
}

// ===== fused GATv2 edge phase + LayerNorm + ReLU, one block per node =====
// wave h owns head h's 64 channels. Streaming softmax WITHOUT max-subtraction
// (scores are O(+-5) for this model; exp() overflows only past 88).
__global__ __launch_bounds__(256)
void gat_fused_kernel(const _Float16* __restrict__ xl, const _Float16* __restrict__ xr,
                      const int* __restrict__ rowptr, const int* __restrict__ csr_src,
                      const float* __restrict__ att,
                      const float* __restrict__ bias, const float* __restrict__ g,
                      const float* __restrict__ be,
                      float* __restrict__ out32, _Float16* __restrict__ out16,
                      int write32)
{
    int n = blockIdx.x;
    int tid = threadIdx.x;
    int h = tid >> 6, lane = tid & 63;
    int start = rowptr[n], end = rowptr[n + 1];

    float xr_v  = (float)xr[n * D + tid];
    float att_v = att[tid];

    float den = 0.0f, num = 0.0f;

    int i = start;
    for (; i + 2 <= end; i += 2) {
        int s0 = csr_src[i], s1 = csr_src[i + 1];   // block-uniform -> scalar loads
        float x0 = (float)xl[s0 * D + tid];
        float x1 = (float)xl[s1 * D + tid];
        float v0 = x0 + xr_v; v0 = ((v0 > 0.0f) ? v0 : v0 * NEG_SLOPE) * att_v;
        float v1 = x1 + xr_v; v1 = ((v1 > 0.0f) ? v1 : v1 * NEG_SLOPE) * att_v;
        #pragma unroll
        for (int o = 1; o < 64; o <<= 1) {
            v0 += __shfl_xor(v0, o, 64);
            v1 += __shfl_xor(v1, o, 64);
        }
        float p0 = __expf(v0), p1 = __expf(v1);
        den += p0 + p1;
        num = fmaf(p0, x0, num);
        num = fmaf(p1, x1, num);
    }
    if (i < end) {
        int s0 = csr_src[i];
        float x0 = (float)xl[s0 * D + tid];
        float v0 = x0 + xr_v; v0 = ((v0 > 0.0f) ? v0 : v0 * NEG_SLOPE) * att_v;
        #pragma unroll
        for (int o = 1; o < 64; o <<= 1) v0 += __shfl_xor(v0, o, 64);
        float p0 = __expf(v0);
        den += p0;
        num = fmaf(p0, x0, num);
    }

    float acc = bias[tid] + num / den;

    // LayerNorm over the 256 channels of this block
    __shared__ float red[8];
    float wsum = acc, wsq = acc * acc;
    #pragma unroll
    for (int o = 1; o < 64; o <<= 1) {
        wsum += __shfl_xor(wsum, o, 64);
        wsq  += __shfl_xor(wsq,  o, 64);
    }
    if (lane == 0) { red[h] = wsum; red[4 + h] = wsq; }
    __syncthreads();
    float tot  = red[0] + red[1] + red[2] + red[3];
    float tot2 = red[4] + red[5] + red[6] + red[7];
    float mu = tot * (1.0f / 256.0f);
    float var = tot2 * (1.0f / 256.0f) - mu * mu;
    float rstd = rsqrtf(var + LN_EPS);

    float o = fmaxf((acc - mu) * rstd * g[tid] + be[tid], 0.0f);
    if (write32) out32[n * D + tid] = o;
    else         out16[n * D + tid] = (_Float16)o;
}

// ================= launch =================
extern "C" void kernel_launch(void* const* d_in, const int* in_sizes, int n_in,
                              void* d_out, int out_size, void* d_ws, size_t ws_size,
                              hipStream_t stream)
{
    const float* x  = (const float*)d_in[0];
    const int*   ei = (const int*)d_in[1];

    char* ws = (char*)d_ws;
    size_t off = 0;
    _Float16* h16   = (_Float16*)(ws + off); off += (size_t)N_NODES * D * 2;      // 10.24 MB
    _Float16* xl    = (_Float16*)(ws + off); off += (size_t)N_NODES * D * 2;      // 10.24 MB
    _Float16* xr    = (_Float16*)(ws + off); off += (size_t)N_NODES * D * 2;      // 10.24 MB
    _Float16* Wt    = (_Float16*)(ws + off); off += (size_t)2 * 256 * 256 * 2;
    int* rowptr     = (int*)(ws + off);      off += (size_t)(N_NODES + 32) * 4;
    int* cursor     = (int*)(ws + off);      off += (size_t)N_NODES * 4;
    int* csr_src    = (int*)(ws + off);      off += (size_t)EP * 4;

    // one-time per call
    convert_x_kernel<<<(N_NODES * D / 4 + 255) / 256, 256, 0, stream>>>(x, h16);
    csr_zero_kernel<<<(N_NODES + 255) / 256, 256, 0, stream>>>(cursor);          // cursor as deg
    csr_hist_kernel<<<(EP + 255) / 256, 256, 0, stream>>>(ei, cursor);
    csr_scan_kernel<<<1, 1024, 0, stream>>>(cursor, rowptr, cursor);
    csr_scatter_kernel<<<(EP + 255) / 256, 256, 0, stream>>>(ei, cursor, csr_src);

    dim3 gemm_grid((N_NODES + BM - 1) / BM, 256 / BN, 2);   // (157, 4, 2)

    for (int l = 0; l < 4; ++l) {
        const float* Wl   = (const float*)d_in[2 + 6 * l + 0];
        const float* Wr   = (const float*)d_in[2 + 6 * l + 1];
        const float* att  = (const float*)d_in[2 + 6 * l + 2];
        const float* bias = (const float*)d_in[2 + 6 * l + 3];
        const float* g    = (const float*)d_in[2 + 6 * l + 4];
        const float* be   = (const float*)d_in[2 + 6 * l + 5];

        convw_kernel<<<dim3(4, 4, 2), 256, 0, stream>>>(Wl, Wr, Wt);
        gemm_f16_kernel<<<gemm_grid, 256, 0, stream>>>(h16, Wt, xl, xr, N_NODES);
        gat_fused_kernel<<<N_NODES, 256, 0, stream>>>(xl, xr, rowptr, csr_src, att,
                                                      bias, g, be,
                                                      (float*)d_out, h16, (l == 3) ? 1 : 0);
    }
}

// Round 4
// 444.669 us; speedup vs baseline: 6.0536x; 1.4961x over previous
//
#include <hip/hip_runtime.h>
#include <math.h>

#define N_NODES 20000
#define E_EDGES 320000
#define EP (E_EDGES + N_NODES)   // 340000 edges incl. self-loops
#define D 256
#define NHEAD 4
#define CH 64
#define NEG_SLOPE 0.2f
#define LN_EPS 1e-5f

typedef _Float16 half8_t __attribute__((ext_vector_type(8)));
typedef _Float16 half4_t __attribute__((ext_vector_type(4)));
typedef float   float4_t __attribute__((ext_vector_type(4)));

// ================= one-time: convert x (fp32) -> f16 =================
__global__ __launch_bounds__(256)
void convert_x_kernel(const float* __restrict__ x, _Float16* __restrict__ h16)
{
    int i = blockIdx.x * 256 + threadIdx.x;          // one float4 per thread
    if (i >= N_NODES * D / 4) return;
    float4 v = reinterpret_cast<const float4*>(x)[i];
    half4_t o;
    o.x = (_Float16)v.x; o.y = (_Float16)v.y; o.z = (_Float16)v.z; o.w = (_Float16)v.w;
    reinterpret_cast<half4_t*>(h16)[i] = o;
}

// ================= CSR build =================
__global__ __launch_bounds__(256)
void csr_zero_kernel(int* __restrict__ deg)
{
    int i = blockIdx.x * 256 + threadIdx.x;
    if (i < N_NODES) deg[i] = 0;
}

__global__ __launch_bounds__(256)
void csr_hist_kernel(const int* __restrict__ ei, int* __restrict__ deg)
{
    int e = blockIdx.x * 256 + threadIdx.x;
    if (e >= EP) return;
    int dst = (e < E_EDGES) ? ei[E_EDGES + e] : (e - E_EDGES);
    atomicAdd(&deg[dst], 1);
}

__global__ __launch_bounds__(1024)
void csr_scan_kernel(const int* __restrict__ deg, int* __restrict__ rowptr,
                     int* __restrict__ cursor)
{
    __shared__ int wsum[16];
    __shared__ int carry;
    int t = threadIdx.x, lane = t & 63, w = t >> 6;
    if (t == 0) carry = 0;
    __syncthreads();
    for (int base = 0; base < N_NODES; base += 1024) {
        int i = base + t;
        int v = (i < N_NODES) ? deg[i] : 0;
        int x = v;
        #pragma unroll
        for (int o = 1; o < 64; o <<= 1) {
            int y = __shfl_up(x, o, 64);
            if (lane >= o) x += y;
        }
        if (lane == 63) wsum[w] = x;
        __syncthreads();
        if (t == 0) {
            int s = carry;
            #pragma unroll
            for (int k = 0; k < 16; ++k) { int tmp = wsum[k]; wsum[k] = s; s += tmp; }
            carry = s;
        }
        __syncthreads();
        int excl = wsum[w] + x - v;
        if (i < N_NODES) { rowptr[i] = excl; cursor[i] = excl; }
        __syncthreads();
    }
    if (t == 0) rowptr[N_NODES] = carry;
}

__global__ __launch_bounds__(256)
void csr_scatter_kernel(const int* __restrict__ ei, int* __restrict__ cursor,
                        int* __restrict__ csr_src)
{
    int e = blockIdx.x * 256 + threadIdx.x;
    if (e >= EP) return;
    int src, dst;
    if (e < E_EDGES) { src = ei[e]; dst = ei[E_EDGES + e]; }
    else             { src = dst = e - E_EDGES; }
    int pos = atomicAdd(&cursor[dst], 1);
    csr_src[pos] = src;
}

// ================= per-layer: W convert + transpose to f16 [n][k] =================
// grid (4,4,2), block 256
__global__ __launch_bounds__(256)
void convw_kernel(const float* __restrict__ Wl, const float* __restrict__ Wr,
                  _Float16* __restrict__ Wt)
{
    __shared__ float tile[64][65];
    const float* W = blockIdx.z ? Wr : Wl;
    _Float16* out = Wt + blockIdx.z * 65536;
    int bx = blockIdx.x * 64, by = blockIdx.y * 64;
    int t = threadIdx.x;
    #pragma unroll
    for (int i = 0; i < 16; ++i) {
        int idx = t + i * 256;
        int kk = idx >> 6, nn = idx & 63;
        tile[kk][nn] = W[(by + kk) * 256 + bx + nn];
    }
    __syncthreads();
    #pragma unroll
    for (int i = 0; i < 16; ++i) {
        int idx = t + i * 256;
        int nn = idx >> 6, kk = idx & 63;
        out[(bx + nn) * 256 + by + kk] = (_Float16)tile[kk][nn];
    }
}

// ================= GEMM: X = A16 @ W (f16 MFMA, fp32 accum, f16 out) =================
// A16: [M][256] f16 row-major; Wt: [2][256][256] f16 laid out [n][k]
// grid (157, 4, 2), block 256 (4 waves). BM=128, BN=64, BK=32.
#define BM 128
#define BN 64
#define BK 32
__global__ __launch_bounds__(256)
void gemm_f16_kernel(const _Float16* __restrict__ A16, const _Float16* __restrict__ Wt,
                     _Float16* __restrict__ X0, _Float16* __restrict__ X1, int nrows)
{
    const _Float16* W = Wt + blockIdx.z * 65536;
    _Float16* X = blockIdx.z ? X1 : X0;
    const int row0 = blockIdx.x * BM;
    const int col0 = blockIdx.y * BN;

    __shared__ _Float16 As[BM][BK + 8];   // pad 8 f16: row stride 80B, 16B-aligned
    __shared__ _Float16 Bs[BN][BK + 8];

    const int tid  = threadIdx.x;
    const int wave = tid >> 6, lane = tid & 63;
    const int quad = lane >> 4, l16 = lane & 15;

    float4_t acc[2][4];
    #pragma unroll
    for (int i = 0; i < 2; ++i)
        #pragma unroll
        for (int j = 0; j < 4; ++j) acc[i][j] = (float4_t)0.0f;

    for (int k0 = 0; k0 < 256; k0 += BK) {
        // stage A: 128x32 f16 -> 2x 16B loads/thread
        #pragma unroll
        for (int i = 0; i < 2; ++i) {
            int idx = tid + i * 256;
            int r = idx >> 2, kk = (idx & 3) * 8;
            int gr = row0 + r;
            half8_t v = (half8_t)(_Float16)0.0f;
            if (gr < nrows)
                v = *reinterpret_cast<const half8_t*>(A16 + gr * 256 + k0 + kk);
            *reinterpret_cast<half8_t*>(&As[r][kk]) = v;
        }
        // stage B: 64x32 f16 -> 1x 16B load/thread
        {
            int r = tid >> 2, kk = (tid & 3) * 8;
            half8_t v = *reinterpret_cast<const half8_t*>(W + (col0 + r) * 256 + k0 + kk);
            *reinterpret_cast<half8_t*>(&Bs[r][kk]) = v;
        }
        __syncthreads();

        half8_t af[2], bf[4];
        #pragma unroll
        for (int i = 0; i < 2; ++i)
            af[i] = *reinterpret_cast<const half8_t*>(&As[wave * 32 + i * 16 + l16][quad * 8]);
        #pragma unroll
        for (int j = 0; j < 4; ++j)
            bf[j] = *reinterpret_cast<const half8_t*>(&Bs[j * 16 + l16][quad * 8]);
        #pragma unroll
        for (int i = 0; i < 2; ++i)
            #pragma unroll
            for (int j = 0; j < 4; ++j)
                acc[i][j] = __builtin_amdgcn_mfma_f32_16x16x32_f16(af[i], bf[j], acc[i][j], 0, 0, 0);
        __syncthreads();
    }
    // epilogue: D[row=quad*4+r][col=l16] per 16x16 tile
    #pragma unroll
    for (int i = 0; i < 2; ++i) {
        #pragma unroll
        for (int r = 0; r < 4; ++r) {
            int gr = row0 + wave * 32 + i * 16 + quad * 4 + r;
            if (gr < nrows) {
                #pragma unroll
                for (int j = 0; j < 4; ++j)
                    X[gr * 256 + col0 + j * 16 + l16] = (_Float16)acc[i][j][r];
            }
        }
    }
}

// ===== fused GATv2 edge phase + LayerNorm + ReLU, one block per node =====
// One WAVE per edge: lane l covers channels 4l..4l+3 (within head l>>4).
// Score reduction = 4 shuffle steps within 16-lane groups. Streaming softmax
// without max-subtraction (scores are O(+-5); exp overflows only past 88).
__global__ __launch_bounds__(256)
void gat_fused_kernel(const _Float16* __restrict__ xl, const _Float16* __restrict__ xr,
                      const int* __restrict__ rowptr, const int* __restrict__ csr_src,
                      const float* __restrict__ att,
                      const float* __restrict__ bias, const float* __restrict__ g,
                      const float* __restrict__ be,
                      float* __restrict__ out32, _Float16* __restrict__ out16,
                      int write32)
{
    const int n = blockIdx.x;
    const int tid = threadIdx.x;
    const int w = tid >> 6, lane = tid & 63;
    const int start = rowptr[n], end = rowptr[n + 1];
    const int c0 = lane * 4;

    float4 xr_v, att_v;
    {
        half4_t xh = *reinterpret_cast<const half4_t*>(xr + n * D + c0);
        xr_v = make_float4((float)xh.x, (float)xh.y, (float)xh.z, (float)xh.w);
        att_v = *reinterpret_cast<const float4*>(att + c0);
    }

    float den = 0.0f;
    float4 num = make_float4(0.0f, 0.0f, 0.0f, 0.0f);

    int i = start + w;
    for (; i + 4 < end; i += 8) {   // 2 edges per wave per iteration
        int s0 = csr_src[i];
        int s1 = csr_src[i + 4];
        half4_t ha = *reinterpret_cast<const half4_t*>(xl + s0 * D + c0);
        half4_t hb = *reinterpret_cast<const half4_t*>(xl + s1 * D + c0);
        float a0=(float)ha.x, a1=(float)ha.y, a2=(float)ha.z, a3=(float)ha.w;
        float b0=(float)hb.x, b1=(float)hb.y, b2=(float)hb.z, b3=(float)hb.w;

        float t, va = 0.0f, vb = 0.0f;
        t = a0 + xr_v.x; va = fmaf((t > 0.f) ? t : t * NEG_SLOPE, att_v.x, va);
        t = a1 + xr_v.y; va = fmaf((t > 0.f) ? t : t * NEG_SLOPE, att_v.y, va);
        t = a2 + xr_v.z; va = fmaf((t > 0.f) ? t : t * NEG_SLOPE, att_v.z, va);
        t = a3 + xr_v.w; va = fmaf((t > 0.f) ? t : t * NEG_SLOPE, att_v.w, va);
        t = b0 + xr_v.x; vb = fmaf((t > 0.f) ? t : t * NEG_SLOPE, att_v.x, vb);
        t = b1 + xr_v.y; vb = fmaf((t > 0.f) ? t : t * NEG_SLOPE, att_v.y, vb);
        t = b2 + xr_v.z; vb = fmaf((t > 0.f) ? t : t * NEG_SLOPE, att_v.z, vb);
        t = b3 + xr_v.w; vb = fmaf((t > 0.f) ? t : t * NEG_SLOPE, att_v.w, vb);
        #pragma unroll
        for (int o = 1; o < 16; o <<= 1) {
            va += __shfl_xor(va, o, 64);
            vb += __shfl_xor(vb, o, 64);
        }
        float pa = __expf(va), pb = __expf(vb);
        den += pa + pb;
        num.x = fmaf(pa, a0, num.x); num.x = fmaf(pb, b0, num.x);
        num.y = fmaf(pa, a1, num.y); num.y = fmaf(pb, b1, num.y);
        num.z = fmaf(pa, a2, num.z); num.z = fmaf(pb, b2, num.z);
        num.w = fmaf(pa, a3, num.w); num.w = fmaf(pb, b3, num.w);
    }
    if (i < end) {
        int s0 = csr_src[i];
        half4_t ha = *reinterpret_cast<const half4_t*>(xl + s0 * D + c0);
        float a0=(float)ha.x, a1=(float)ha.y, a2=(float)ha.z, a3=(float)ha.w;
        float t, va = 0.0f;
        t = a0 + xr_v.x; va = fmaf((t > 0.f) ? t : t * NEG_SLOPE, att_v.x, va);
        t = a1 + xr_v.y; va = fmaf((t > 0.f) ? t : t * NEG_SLOPE, att_v.y, va);
        t = a2 + xr_v.z; va = fmaf((t > 0.f) ? t : t * NEG_SLOPE, att_v.z, va);
        t = a3 + xr_v.w; va = fmaf((t > 0.f) ? t : t * NEG_SLOPE, att_v.w, va);
        #pragma unroll
        for (int o = 1; o < 16; o <<= 1) va += __shfl_xor(va, o, 64);
        float pa = __expf(va);
        den += pa;
        num.x = fmaf(pa, a0, num.x);
        num.y = fmaf(pa, a1, num.y);
        num.z = fmaf(pa, a2, num.z);
        num.w = fmaf(pa, a3, num.w);
    }

    // combine the 4 waves' partials in LDS
    __shared__ float lnum[4][D];      // 4 KB
    __shared__ float lden[4][NHEAD];
    *reinterpret_cast<float4*>(&lnum[w][c0]) = num;
    if ((lane & 15) == 0) lden[w][lane >> 4] = den;
    __syncthreads();

    // per-channel epilogue: thread tid owns channel tid
    const int c = tid, hh = c >> 6, lane2 = tid & 63;
    float numc = lnum[0][c] + lnum[1][c] + lnum[2][c] + lnum[3][c];
    float denc = lden[0][hh] + lden[1][hh] + lden[2][hh] + lden[3][hh];
    float acc = bias[c] + numc / denc;

    // LayerNorm over 256 channels
    __shared__ float red[8];
    float wsum = acc, wsq = acc * acc;
    #pragma unroll
    for (int o = 1; o < 64; o <<= 1) {
        wsum += __shfl_xor(wsum, o, 64);
        wsq  += __shfl_xor(wsq,  o, 64);
    }
    if (lane2 == 0) { red[hh] = wsum; red[4 + hh] = wsq; }
    __syncthreads();
    float tot  = red[0] + red[1] + red[2] + red[3];
    float tot2 = red[4] + red[5] + red[6] + red[7];
    float mu = tot * (1.0f / 256.0f);
    float var = tot2 * (1.0f / 256.0f) - mu * mu;
    float rstd = rsqrtf(var + LN_EPS);

    float o = fmaxf((acc - mu) * rstd * g[c] + be[c], 0.0f);
    if (write32) out32[n * D + c] = o;
    else         out16[n * D + c] = (_Float16)o;
}

// ================= launch =================
extern "C" void kernel_launch(void* const* d_in, const int* in_sizes, int n_in,
                              void* d_out, int out_size, void* d_ws, size_t ws_size,
                              hipStream_t stream)
{
    const float* x  = (const float*)d_in[0];
    const int*   ei = (const int*)d_in[1];

    char* ws = (char*)d_ws;
    size_t off = 0;
    _Float16* h16   = (_Float16*)(ws + off); off += (size_t)N_NODES * D * 2;      // 10.24 MB
    _Float16* xl    = (_Float16*)(ws + off); off += (size_t)N_NODES * D * 2;      // 10.24 MB
    _Float16* xr    = (_Float16*)(ws + off); off += (size_t)N_NODES * D * 2;      // 10.24 MB
    _Float16* Wt    = (_Float16*)(ws + off); off += (size_t)2 * 256 * 256 * 2;
    int* rowptr     = (int*)(ws + off);      off += (size_t)(N_NODES + 32) * 4;
    int* cursor     = (int*)(ws + off);      off += (size_t)N_NODES * 4;
    int* csr_src    = (int*)(ws + off);      off += (size_t)EP * 4;

    // one-time per call
    convert_x_kernel<<<(N_NODES * D / 4 + 255) / 256, 256, 0, stream>>>(x, h16);
    csr_zero_kernel<<<(N_NODES + 255) / 256, 256, 0, stream>>>(cursor);          // cursor as deg
    csr_hist_kernel<<<(EP + 255) / 256, 256, 0, stream>>>(ei, cursor);
    csr_scan_kernel<<<1, 1024, 0, stream>>>(cursor, rowptr, cursor);
    csr_scatter_kernel<<<(EP + 255) / 256, 256, 0, stream>>>(ei, cursor, csr_src);

    dim3 gemm_grid((N_NODES + BM - 1) / BM, 256 / BN, 2);   // (157, 4, 2)

    for (int l = 0; l < 4; ++l) {
        const float* Wl   = (const float*)d_in[2 + 6 * l + 0];
        const float* Wr   = (const float*)d_in[2 + 6 * l + 1];
        const float* att  = (const float*)d_in[2 + 6 * l + 2];
        const float* bias = (const float*)d_in[2 + 6 * l + 3];
        const float* g    = (const float*)d_in[2 + 6 * l + 4];
        const float* be   = (const float*)d_in[2 + 6 * l + 5];

        convw_kernel<<<dim3(4, 4, 2), 256, 0, stream>>>(Wl, Wr, Wt);
        gemm_f16_kernel<<<gemm_grid, 256, 0, stream>>>(h16, Wt, xl, xr, N_NODES);
        gat_fused_kernel<<<N_NODES, 256, 0, stream>>>(xl, xr, rowptr, csr_src, att,
                                                      bias, g, be,
                                                      (float*)d_out, h16, (l == 3) ? 1 : 0);
    }
}

// Round 5
// 437.043 us; speedup vs baseline: 6.1593x; 1.0174x over previous
//
#include <hip/hip_runtime.h>
#include <math.h>

#define N_NODES 20000
#define E_EDGES 320000
#define EP (E_EDGES + N_NODES)   // 340000 edges incl. self-loops
#define D 256
#define NHEAD 4
#define CH 64
#define NEG_SLOPE 0.2f
#define LN_EPS 1e-5f

typedef _Float16 half8_t __attribute__((ext_vector_type(8)));
typedef _Float16 half4_t __attribute__((ext_vector_type(4)));
typedef _Float16 half2_t __attribute__((ext_vector_type(2)));
typedef float   float4_t __attribute__((ext_vector_type(4)));

// ================= one-time: convert x (fp32) -> f16 =================
__global__ __launch_bounds__(256)
void convert_x_kernel(const float* __restrict__ x, _Float16* __restrict__ h16)
{
    int i = blockIdx.x * 256 + threadIdx.x;          // one float4 per thread
    if (i >= N_NODES * D / 4) return;
    float4 v = reinterpret_cast<const float4*>(x)[i];
    half4_t o;
    o.x = (_Float16)v.x; o.y = (_Float16)v.y; o.z = (_Float16)v.z; o.w = (_Float16)v.w;
    reinterpret_cast<half4_t*>(h16)[i] = o;
}

// ================= CSR build =================
__global__ __launch_bounds__(256)
void csr_zero_kernel(int* __restrict__ deg)
{
    int i = blockIdx.x * 256 + threadIdx.x;
    if (i < N_NODES) deg[i] = 0;
}

__global__ __launch_bounds__(256)
void csr_hist_kernel(const int* __restrict__ ei, int* __restrict__ deg)
{
    int e = blockIdx.x * 256 + threadIdx.x;
    if (e >= EP) return;
    int dst = (e < E_EDGES) ? ei[E_EDGES + e] : (e - E_EDGES);
    atomicAdd(&deg[dst], 1);
}

__global__ __launch_bounds__(1024)
void csr_scan_kernel(const int* __restrict__ deg, int* __restrict__ rowptr,
                     int* __restrict__ cursor)
{
    __shared__ int wsum[16];
    __shared__ int carry;
    int t = threadIdx.x, lane = t & 63, w = t >> 6;
    if (t == 0) carry = 0;
    __syncthreads();
    for (int base = 0; base < N_NODES; base += 1024) {
        int i = base + t;
        int v = (i < N_NODES) ? deg[i] : 0;
        int x = v;
        #pragma unroll
        for (int o = 1; o < 64; o <<= 1) {
            int y = __shfl_up(x, o, 64);
            if (lane >= o) x += y;
        }
        if (lane == 63) wsum[w] = x;
        __syncthreads();
        if (t == 0) {
            int s = carry;
            #pragma unroll
            for (int k = 0; k < 16; ++k) { int tmp = wsum[k]; wsum[k] = s; s += tmp; }
            carry = s;
        }
        __syncthreads();
        int excl = wsum[w] + x - v;
        if (i < N_NODES) { rowptr[i] = excl; cursor[i] = excl; }
        __syncthreads();
    }
    if (t == 0) rowptr[N_NODES] = carry;
}

__global__ __launch_bounds__(256)
void csr_scatter_kernel(const int* __restrict__ ei, int* __restrict__ cursor,
                        int* __restrict__ csr_src)
{
    int e = blockIdx.x * 256 + threadIdx.x;
    if (e >= EP) return;
    int src, dst;
    if (e < E_EDGES) { src = ei[e]; dst = ei[E_EDGES + e]; }
    else             { src = dst = e - E_EDGES; }
    int pos = atomicAdd(&cursor[dst], 1);
    csr_src[pos] = src;
}

// ===== upfront: convert+transpose ALL 8 weight matrices to f16 [n][k] =====
struct WPtrs { const float* p[8]; };
// grid (4,4,8), block 256; z = layer*2 + side
__global__ __launch_bounds__(256)
void convw_all_kernel(WPtrs wp, _Float16* __restrict__ Wt_all)
{
    __shared__ float tile[64][65];
    const float* W = wp.p[blockIdx.z];
    _Float16* out = Wt_all + (size_t)blockIdx.z * 65536;
    int bx = blockIdx.x * 64, by = blockIdx.y * 64;
    int t = threadIdx.x;
    #pragma unroll
    for (int i = 0; i < 16; ++i) {
        int idx = t + i * 256;
        int kk = idx >> 6, nn = idx & 63;
        tile[kk][nn] = W[(by + kk) * 256 + bx + nn];
    }
    __syncthreads();
    #pragma unroll
    for (int i = 0; i < 16; ++i) {
        int idx = t + i * 256;
        int nn = idx >> 6, kk = idx & 63;
        out[(bx + nn) * 256 + by + kk] = (_Float16)tile[kk][nn];
    }
}

// ================= GEMM: X = A16 @ W (f16 MFMA, fp32 accum, f16 out) =================
// A16: [M][256] f16 row-major; Wt: [2][256][256] f16 laid out [n][k]
// grid (157, 4, 2), block 256 (4 waves). BM=128, BN=64, BK=32.
#define BM 128
#define BN 64
#define BK 32
__global__ __launch_bounds__(256)
void gemm_f16_kernel(const _Float16* __restrict__ A16, const _Float16* __restrict__ Wt,
                     _Float16* __restrict__ X0, _Float16* __restrict__ X1, int nrows)
{
    const _Float16* W = Wt + blockIdx.z * 65536;
    _Float16* X = blockIdx.z ? X1 : X0;
    const int row0 = blockIdx.x * BM;
    const int col0 = blockIdx.y * BN;

    __shared__ _Float16 As[BM][BK + 8];   // pad 8 f16: row stride 80B, 16B-aligned
    __shared__ _Float16 Bs[BN][BK + 8];

    const int tid  = threadIdx.x;
    const int wave = tid >> 6, lane = tid & 63;
    const int quad = lane >> 4, l16 = lane & 15;

    float4_t acc[2][4];
    #pragma unroll
    for (int i = 0; i < 2; ++i)
        #pragma unroll
        for (int j = 0; j < 4; ++j) acc[i][j] = (float4_t)0.0f;

    for (int k0 = 0; k0 < 256; k0 += BK) {
        // stage A: 128x32 f16 -> 2x 16B loads/thread
        #pragma unroll
        for (int i = 0; i < 2; ++i) {
            int idx = tid + i * 256;
            int r = idx >> 2, kk = (idx & 3) * 8;
            int gr = row0 + r;
            half8_t v = (half8_t)(_Float16)0.0f;
            if (gr < nrows)
                v = *reinterpret_cast<const half8_t*>(A16 + gr * 256 + k0 + kk);
            *reinterpret_cast<half8_t*>(&As[r][kk]) = v;
        }
        // stage B: 64x32 f16 -> 1x 16B load/thread
        {
            int r = tid >> 2, kk = (tid & 3) * 8;
            half8_t v = *reinterpret_cast<const half8_t*>(W + (col0 + r) * 256 + k0 + kk);
            *reinterpret_cast<half8_t*>(&Bs[r][kk]) = v;
        }
        __syncthreads();

        half8_t af[2], bf[4];
        #pragma unroll
        for (int i = 0; i < 2; ++i)
            af[i] = *reinterpret_cast<const half8_t*>(&As[wave * 32 + i * 16 + l16][quad * 8]);
        #pragma unroll
        for (int j = 0; j < 4; ++j)
            bf[j] = *reinterpret_cast<const half8_t*>(&Bs[j * 16 + l16][quad * 8]);
        #pragma unroll
        for (int i = 0; i < 2; ++i)
            #pragma unroll
            for (int j = 0; j < 4; ++j)
                acc[i][j] = __builtin_amdgcn_mfma_f32_16x16x32_f16(af[i], bf[j], acc[i][j], 0, 0, 0);
        __syncthreads();
    }
    // epilogue: D[row=quad*4+r][col=l16] per 16x16 tile
    #pragma unroll
    for (int i = 0; i < 2; ++i) {
        #pragma unroll
        for (int r = 0; r < 4; ++r) {
            int gr = row0 + wave * 32 + i * 16 + quad * 4 + r;
            if (gr < nrows) {
                #pragma unroll
                for (int j = 0; j < 4; ++j)
                    X[gr * 256 + col0 + j * 16 + l16] = (_Float16)acc[i][j][r];
            }
        }
    }
}

// ===== fused GATv2 edge phase + LayerNorm + ReLU, one block per node =====
// One WAVE per edge: lane l covers channels 4l..4l+3 (within head l>>4).
// Packed-f16 score path: pk_add, leaky = pk_max(t, 0.2t), v_dot2_f32_f16.
// Streaming softmax without max-subtraction (scores are O(+-5)).
__global__ __launch_bounds__(256)
void gat_fused_kernel(const _Float16* __restrict__ xl, const _Float16* __restrict__ xr,
                      const int* __restrict__ rowptr, const int* __restrict__ csr_src,
                      const float* __restrict__ att,
                      const float* __restrict__ bias, const float* __restrict__ g,
                      const float* __restrict__ be,
                      float* __restrict__ out32, _Float16* __restrict__ out16,
                      int write32)
{
    const int n = blockIdx.x;
    const int tid = threadIdx.x;
    const int w = tid >> 6, lane = tid & 63;
    const int start = rowptr[n], end = rowptr[n + 1];
    const int c0 = lane * 4;

    half2_t xr01, xr23, att01, att23;
    {
        half4_t xh = *reinterpret_cast<const half4_t*>(xr + n * D + c0);
        xr01.x = xh.x; xr01.y = xh.y; xr23.x = xh.z; xr23.y = xh.w;
        float4 av = *reinterpret_cast<const float4*>(att + c0);
        att01.x = (_Float16)av.x; att01.y = (_Float16)av.y;
        att23.x = (_Float16)av.z; att23.y = (_Float16)av.w;
    }
    const half2_t k02 = {(_Float16)NEG_SLOPE, (_Float16)NEG_SLOPE};

    float den = 0.0f;
    float4 num = make_float4(0.0f, 0.0f, 0.0f, 0.0f);

    int i = start + w;
    for (; i + 4 < end; i += 8) {   // 2 edges per wave per iteration
        int s0 = csr_src[i];
        int s1 = csr_src[i + 4];
        half4_t ha = *reinterpret_cast<const half4_t*>(xl + s0 * D + c0);
        half4_t hb = *reinterpret_cast<const half4_t*>(xl + s1 * D + c0);

        half2_t a01 = {ha.x, ha.y}, a23 = {ha.z, ha.w};
        half2_t b01 = {hb.x, hb.y}, b23 = {hb.z, hb.w};
        half2_t t0 = a01 + xr01, t1 = a23 + xr23;
        half2_t u0 = b01 + xr01, u1 = b23 + xr23;
        t0 = __builtin_elementwise_max(t0, t0 * k02);
        t1 = __builtin_elementwise_max(t1, t1 * k02);
        u0 = __builtin_elementwise_max(u0, u0 * k02);
        u1 = __builtin_elementwise_max(u1, u1 * k02);
        float va = __builtin_amdgcn_fdot2(t0, att01, 0.0f, false);
        va       = __builtin_amdgcn_fdot2(t1, att23, va,   false);
        float vb = __builtin_amdgcn_fdot2(u0, att01, 0.0f, false);
        vb       = __builtin_amdgcn_fdot2(u1, att23, vb,   false);
        #pragma unroll
        for (int o = 1; o < 16; o <<= 1) {
            va += __shfl_xor(va, o, 64);
            vb += __shfl_xor(vb, o, 64);
        }
        float pa = __expf(va), pb = __expf(vb);
        den += pa + pb;
        num.x = fmaf(pa, (float)ha.x, num.x); num.x = fmaf(pb, (float)hb.x, num.x);
        num.y = fmaf(pa, (float)ha.y, num.y); num.y = fmaf(pb, (float)hb.y, num.y);
        num.z = fmaf(pa, (float)ha.z, num.z); num.z = fmaf(pb, (float)hb.z, num.z);
        num.w = fmaf(pa, (float)ha.w, num.w); num.w = fmaf(pb, (float)hb.w, num.w);
    }
    if (i < end) {
        int s0 = csr_src[i];
        half4_t ha = *reinterpret_cast<const half4_t*>(xl + s0 * D + c0);
        half2_t a01 = {ha.x, ha.y}, a23 = {ha.z, ha.w};
        half2_t t0 = a01 + xr01, t1 = a23 + xr23;
        t0 = __builtin_elementwise_max(t0, t0 * k02);
        t1 = __builtin_elementwise_max(t1, t1 * k02);
        float va = __builtin_amdgcn_fdot2(t0, att01, 0.0f, false);
        va       = __builtin_amdgcn_fdot2(t1, att23, va,   false);
        #pragma unroll
        for (int o = 1; o < 16; o <<= 1) va += __shfl_xor(va, o, 64);
        float pa = __expf(va);
        den += pa;
        num.x = fmaf(pa, (float)ha.x, num.x);
        num.y = fmaf(pa, (float)ha.y, num.y);
        num.z = fmaf(pa, (float)ha.z, num.z);
        num.w = fmaf(pa, (float)ha.w, num.w);
    }

    // combine the 4 waves' partials in LDS
    __shared__ float lnum[4][D];      // 4 KB
    __shared__ float lden[4][NHEAD];
    *reinterpret_cast<float4*>(&lnum[w][c0]) = num;
    if ((lane & 15) == 0) lden[w][lane >> 4] = den;
    __syncthreads();

    // per-channel epilogue: thread tid owns channel tid
    const int c = tid, hh = c >> 6, lane2 = tid & 63;
    float numc = lnum[0][c] + lnum[1][c] + lnum[2][c] + lnum[3][c];
    float denc = lden[0][hh] + lden[1][hh] + lden[2][hh] + lden[3][hh];
    float acc = bias[c] + numc / denc;

    // LayerNorm over 256 channels
    __shared__ float red[8];
    float wsum = acc, wsq = acc * acc;
    #pragma unroll
    for (int o = 1; o < 64; o <<= 1) {
        wsum += __shfl_xor(wsum, o, 64);
        wsq  += __shfl_xor(wsq,  o, 64);
    }
    if (lane2 == 0) { red[hh] = wsum; red[4 + hh] = wsq; }
    __syncthreads();
    float tot  = red[0] + red[1] + red[2] + red[3];
    float tot2 = red[4] + red[5] + red[6] + red[7];
    float mu = tot * (1.0f / 256.0f);
    float var = tot2 * (1.0f / 256.0f) - mu * mu;
    float rstd = rsqrtf(var + LN_EPS);

    float o = fmaxf((acc - mu) * rstd * g[c] + be[c], 0.0f);
    if (write32) out32[n * D + c] = o;
    else         out16[n * D + c] = (_Float16)o;
}

// ================= launch =================
extern "C" void kernel_launch(void* const* d_in, const int* in_sizes, int n_in,
                              void* d_out, int out_size, void* d_ws, size_t ws_size,
                              hipStream_t stream)
{
    const float* x  = (const float*)d_in[0];
    const int*   ei = (const int*)d_in[1];

    char* ws = (char*)d_ws;
    size_t off = 0;
    _Float16* h16   = (_Float16*)(ws + off); off += (size_t)N_NODES * D * 2;      // 10.24 MB
    _Float16* xl    = (_Float16*)(ws + off); off += (size_t)N_NODES * D * 2;      // 10.24 MB
    _Float16* xr    = (_Float16*)(ws + off); off += (size_t)N_NODES * D * 2;      // 10.24 MB
    _Float16* WtA   = (_Float16*)(ws + off); off += (size_t)8 * 65536 * 2;        // 1 MB
    int* rowptr     = (int*)(ws + off);      off += (size_t)(N_NODES + 32) * 4;
    int* cursor     = (int*)(ws + off);      off += (size_t)N_NODES * 4;
    int* csr_src    = (int*)(ws + off);      off += (size_t)EP * 4;

    // one-time per call
    convert_x_kernel<<<(N_NODES * D / 4 + 255) / 256, 256, 0, stream>>>(x, h16);
    csr_zero_kernel<<<(N_NODES + 255) / 256, 256, 0, stream>>>(cursor);          // cursor as deg
    csr_hist_kernel<<<(EP + 255) / 256, 256, 0, stream>>>(ei, cursor);
    csr_scan_kernel<<<1, 1024, 0, stream>>>(cursor, rowptr, cursor);
    csr_scatter_kernel<<<(EP + 255) / 256, 256, 0, stream>>>(ei, cursor, csr_src);

    WPtrs wp;
    for (int l = 0; l < 4; ++l) {
        wp.p[2 * l + 0] = (const float*)d_in[2 + 6 * l + 0];
        wp.p[2 * l + 1] = (const float*)d_in[2 + 6 * l + 1];
    }
    convw_all_kernel<<<dim3(4, 4, 8), 256, 0, stream>>>(wp, WtA);

    dim3 gemm_grid((N_NODES + BM - 1) / BM, 256 / BN, 2);   // (157, 4, 2)

    for (int l = 0; l < 4; ++l) {
        const float* att  = (const float*)d_in[2 + 6 * l + 2];
        const float* bias = (const float*)d_in[2 + 6 * l + 3];
        const float* g    = (const float*)d_in[2 + 6 * l + 4];
        const float* be   = (const float*)d_in[2 + 6 * l + 5];

        gemm_f16_kernel<<<gemm_grid, 256, 0, stream>>>(h16, WtA + (size_t)l * 131072,
                                                       xl, xr, N_NODES);
        gat_fused_kernel<<<N_NODES, 256, 0, stream>>>(xl, xr, rowptr, csr_src, att,
                                                      bias, g, be,
                                                      (float*)d_out, h16, (l == 3) ? 1 : 0);
    }
}

// Round 6
// 429.416 us; speedup vs baseline: 6.2687x; 1.0178x over previous
//
#include <hip/hip_runtime.h>
#include <math.h>

#define N_NODES 20000
#define E_EDGES 320000
#define EP (E_EDGES + N_NODES)   // 340000 edges incl. self-loops
#define D 256
#define NHEAD 4
#define CH 64
#define NEG_SLOPE 0.2f
#define LN_EPS 1e-5f

typedef _Float16 half8_t __attribute__((ext_vector_type(8)));
typedef _Float16 half4_t __attribute__((ext_vector_type(4)));
typedef _Float16 half2_t __attribute__((ext_vector_type(2)));
typedef float   float4_t __attribute__((ext_vector_type(4)));

// ================= one-time: convert x (fp32) -> f16 =================
__global__ __launch_bounds__(256)
void convert_x_kernel(const float* __restrict__ x, _Float16* __restrict__ h16)
{
    int i = blockIdx.x * 256 + threadIdx.x;          // one float4 per thread
    if (i >= N_NODES * D / 4) return;
    float4 v = reinterpret_cast<const float4*>(x)[i];
    half4_t o;
    o.x = (_Float16)v.x; o.y = (_Float16)v.y; o.z = (_Float16)v.z; o.w = (_Float16)v.w;
    reinterpret_cast<half4_t*>(h16)[i] = o;
}

// ================= CSR build =================
__global__ __launch_bounds__(256)
void csr_zero_kernel(int* __restrict__ deg)
{
    int i = blockIdx.x * 256 + threadIdx.x;
    if (i < N_NODES) deg[i] = 0;
}

__global__ __launch_bounds__(256)
void csr_hist_kernel(const int* __restrict__ ei, int* __restrict__ deg)
{
    int e = blockIdx.x * 256 + threadIdx.x;
    if (e >= EP) return;
    int dst = (e < E_EDGES) ? ei[E_EDGES + e] : (e - E_EDGES);
    atomicAdd(&deg[dst], 1);
}

__global__ __launch_bounds__(1024)
void csr_scan_kernel(const int* __restrict__ deg, int* __restrict__ rowptr,
                     int* __restrict__ cursor)
{
    __shared__ int wsum[16];
    __shared__ int carry;
    int t = threadIdx.x, lane = t & 63, w = t >> 6;
    if (t == 0) carry = 0;
    __syncthreads();
    for (int base = 0; base < N_NODES; base += 1024) {
        int i = base + t;
        int v = (i < N_NODES) ? deg[i] : 0;
        int x = v;
        #pragma unroll
        for (int o = 1; o < 64; o <<= 1) {
            int y = __shfl_up(x, o, 64);
            if (lane >= o) x += y;
        }
        if (lane == 63) wsum[w] = x;
        __syncthreads();
        if (t == 0) {
            int s = carry;
            #pragma unroll
            for (int k = 0; k < 16; ++k) { int tmp = wsum[k]; wsum[k] = s; s += tmp; }
            carry = s;
        }
        __syncthreads();
        int excl = wsum[w] + x - v;
        if (i < N_NODES) { rowptr[i] = excl; cursor[i] = excl; }
        __syncthreads();
    }
    if (t == 0) rowptr[N_NODES] = carry;
}

__global__ __launch_bounds__(256)
void csr_scatter_kernel(const int* __restrict__ ei, int* __restrict__ cursor,
                        int* __restrict__ csr_src)
{
    int e = blockIdx.x * 256 + threadIdx.x;
    if (e >= EP) return;
    int src, dst;
    if (e < E_EDGES) { src = ei[e]; dst = ei[E_EDGES + e]; }
    else             { src = dst = e - E_EDGES; }
    int pos = atomicAdd(&cursor[dst], 1);
    csr_src[pos] = src;
}

// ===== upfront: convert+transpose ALL 8 weight matrices to f16 [n][k] =====
struct WPtrs { const float* p[8]; };
// grid (4,4,8), block 256; z = layer*2 + side
__global__ __launch_bounds__(256)
void convw_all_kernel(WPtrs wp, _Float16* __restrict__ Wt_all)
{
    __shared__ float tile[64][65];
    const float* W = wp.p[blockIdx.z];
    _Float16* out = Wt_all + (size_t)blockIdx.z * 65536;
    int bx = blockIdx.x * 64, by = blockIdx.y * 64;
    int t = threadIdx.x;
    #pragma unroll
    for (int i = 0; i < 16; ++i) {
        int idx = t + i * 256;
        int kk = idx >> 6, nn = idx & 63;
        tile[kk][nn] = W[(by + kk) * 256 + bx + nn];
    }
    __syncthreads();
    #pragma unroll
    for (int i = 0; i < 16; ++i) {
        int idx = t + i * 256;
        int nn = idx >> 6, kk = idx & 63;
        out[(bx + nn) * 256 + by + kk] = (_Float16)tile[kk][nn];
    }
}

// ================= GEMM: X = A16 @ W (f16 MFMA, fp32 accum, f16 out) =================
// A16: [M][256] f16 row-major; Wt: [2][256][256] f16 laid out [n][k]
// grid (157, 2, 2): y = 128-col block, z = matrix. block 256 (4 waves).
// BM=128, BN=128, BK=32; wave w computes rows [32w,32w+32) x 128 cols.
#define BM 128
#define BN 128
#define BK 32
__global__ __launch_bounds__(256)
void gemm_f16_kernel(const _Float16* __restrict__ A16, const _Float16* __restrict__ Wt,
                     _Float16* __restrict__ X0, _Float16* __restrict__ X1, int nrows)
{
    const _Float16* W = Wt + blockIdx.z * 65536 + blockIdx.y * (BN * 256);
    _Float16* X = blockIdx.z ? X1 : X0;
    const int row0 = blockIdx.x * BM;
    const int col0 = blockIdx.y * BN;

    __shared__ _Float16 As[BM][BK + 8];   // pad 16B: row stride 80B
    __shared__ _Float16 Bs[BN][BK + 8];

    const int tid  = threadIdx.x;
    const int wave = tid >> 6, lane = tid & 63;
    const int quad = lane >> 4, l16 = lane & 15;

    float4_t acc[2][8];
    #pragma unroll
    for (int i = 0; i < 2; ++i)
        #pragma unroll
        for (int j = 0; j < 8; ++j) acc[i][j] = (float4_t)0.0f;

    const int r_ld  = tid >> 2;            // 0..63 base row for staging
    const int kk_ld = (tid & 3) * 8;       // 0/8/16/24

    for (int k0 = 0; k0 < 256; k0 += BK) {
        // stage A: 128x32 f16 -> 2x 16B loads/thread
        #pragma unroll
        for (int i = 0; i < 2; ++i) {
            int r = r_ld + i * 64;
            int gr = row0 + r;
            half8_t v = (half8_t)(_Float16)0.0f;
            if (gr < nrows)
                v = *reinterpret_cast<const half8_t*>(A16 + gr * 256 + k0 + kk_ld);
            *reinterpret_cast<half8_t*>(&As[r][kk_ld]) = v;
        }
        // stage B: 128x32 f16 -> 2x 16B loads/thread
        #pragma unroll
        for (int i = 0; i < 2; ++i) {
            int r = r_ld + i * 64;
            half8_t v = *reinterpret_cast<const half8_t*>(W + r * 256 + k0 + kk_ld);
            *reinterpret_cast<half8_t*>(&Bs[r][kk_ld]) = v;
        }
        __syncthreads();

        half8_t af[2], bf[8];
        #pragma unroll
        for (int i = 0; i < 2; ++i)
            af[i] = *reinterpret_cast<const half8_t*>(&As[wave * 32 + i * 16 + l16][quad * 8]);
        #pragma unroll
        for (int j = 0; j < 8; ++j)
            bf[j] = *reinterpret_cast<const half8_t*>(&Bs[j * 16 + l16][quad * 8]);
        #pragma unroll
        for (int i = 0; i < 2; ++i)
            #pragma unroll
            for (int j = 0; j < 8; ++j)
                acc[i][j] = __builtin_amdgcn_mfma_f32_16x16x32_f16(af[i], bf[j], acc[i][j], 0, 0, 0);
        __syncthreads();
    }
    // epilogue: D[row=quad*4+r][col=j*16+l16] per 16x16 tile
    #pragma unroll
    for (int i = 0; i < 2; ++i) {
        #pragma unroll
        for (int r = 0; r < 4; ++r) {
            int gr = row0 + wave * 32 + i * 16 + quad * 4 + r;
            if (gr < nrows) {
                #pragma unroll
                for (int j = 0; j < 8; ++j)
                    X[gr * 256 + col0 + j * 16 + l16] = (_Float16)acc[i][j][r];
            }
        }
    }
}

// ===== fused GATv2 edge phase + LayerNorm + ReLU, one block per node =====
// One WAVE per edge: lane l covers channels 4l..4l+3 (within head l>>4).
// Packed-f16 score path: pk_add, leaky = pk_max(t, 0.2t), v_dot2_f32_f16.
// Streaming softmax without max-subtraction (scores are O(+-5)).
__global__ __launch_bounds__(256)
void gat_fused_kernel(const _Float16* __restrict__ xl, const _Float16* __restrict__ xr,
                      const int* __restrict__ rowptr, const int* __restrict__ csr_src,
                      const float* __restrict__ att,
                      const float* __restrict__ bias, const float* __restrict__ g,
                      const float* __restrict__ be,
                      float* __restrict__ out32, _Float16* __restrict__ out16,
                      int write32)
{
    const int n = blockIdx.x;
    const int tid = threadIdx.x;
    const int w = tid >> 6, lane = tid & 63;
    const int start = rowptr[n], end = rowptr[n + 1];
    const int c0 = lane * 4;

    half2_t xr01, xr23, att01, att23;
    {
        half4_t xh = *reinterpret_cast<const half4_t*>(xr + n * D + c0);
        xr01.x = xh.x; xr01.y = xh.y; xr23.x = xh.z; xr23.y = xh.w;
        float4 av = *reinterpret_cast<const float4*>(att + c0);
        att01.x = (_Float16)av.x; att01.y = (_Float16)av.y;
        att23.x = (_Float16)av.z; att23.y = (_Float16)av.w;
    }
    const half2_t k02 = {(_Float16)NEG_SLOPE, (_Float16)NEG_SLOPE};

    float den = 0.0f;
    float4 num = make_float4(0.0f, 0.0f, 0.0f, 0.0f);

    int i = start + w;
    for (; i + 4 < end; i += 8) {   // 2 edges per wave per iteration
        int s0 = csr_src[i];
        int s1 = csr_src[i + 4];
        half4_t ha = *reinterpret_cast<const half4_t*>(xl + s0 * D + c0);
        half4_t hb = *reinterpret_cast<const half4_t*>(xl + s1 * D + c0);

        half2_t a01 = {ha.x, ha.y}, a23 = {ha.z, ha.w};
        half2_t b01 = {hb.x, hb.y}, b23 = {hb.z, hb.w};
        half2_t t0 = a01 + xr01, t1 = a23 + xr23;
        half2_t u0 = b01 + xr01, u1 = b23 + xr23;
        t0 = __builtin_elementwise_max(t0, t0 * k02);
        t1 = __builtin_elementwise_max(t1, t1 * k02);
        u0 = __builtin_elementwise_max(u0, u0 * k02);
        u1 = __builtin_elementwise_max(u1, u1 * k02);
        float va = __builtin_amdgcn_fdot2(t0, att01, 0.0f, false);
        va       = __builtin_amdgcn_fdot2(t1, att23, va,   false);
        float vb = __builtin_amdgcn_fdot2(u0, att01, 0.0f, false);
        vb       = __builtin_amdgcn_fdot2(u1, att23, vb,   false);
        #pragma unroll
        for (int o = 1; o < 16; o <<= 1) {
            va += __shfl_xor(va, o, 64);
            vb += __shfl_xor(vb, o, 64);
        }
        float pa = __expf(va), pb = __expf(vb);
        den += pa + pb;
        num.x = fmaf(pa, (float)ha.x, num.x); num.x = fmaf(pb, (float)hb.x, num.x);
        num.y = fmaf(pa, (float)ha.y, num.y); num.y = fmaf(pb, (float)hb.y, num.y);
        num.z = fmaf(pa, (float)ha.z, num.z); num.z = fmaf(pb, (float)hb.z, num.z);
        num.w = fmaf(pa, (float)ha.w, num.w); num.w = fmaf(pb, (float)hb.w, num.w);
    }
    if (i < end) {
        int s0 = csr_src[i];
        half4_t ha = *reinterpret_cast<const half4_t*>(xl + s0 * D + c0);
        half2_t a01 = {ha.x, ha.y}, a23 = {ha.z, ha.w};
        half2_t t0 = a01 + xr01, t1 = a23 + xr23;
        t0 = __builtin_elementwise_max(t0, t0 * k02);
        t1 = __builtin_elementwise_max(t1, t1 * k02);
        float va = __builtin_amdgcn_fdot2(t0, att01, 0.0f, false);
        va       = __builtin_amdgcn_fdot2(t1, att23, va,   false);
        #pragma unroll
        for (int o = 1; o < 16; o <<= 1) va += __shfl_xor(va, o, 64);
        float pa = __expf(va);
        den += pa;
        num.x = fmaf(pa, (float)ha.x, num.x);
        num.y = fmaf(pa, (float)ha.y, num.y);
        num.z = fmaf(pa, (float)ha.z, num.z);
        num.w = fmaf(pa, (float)ha.w, num.w);
    }

    // combine the 4 waves' partials in LDS
    __shared__ float lnum[4][D];      // 4 KB
    __shared__ float lden[4][NHEAD];
    *reinterpret_cast<float4*>(&lnum[w][c0]) = num;
    if ((lane & 15) == 0) lden[w][lane >> 4] = den;
    __syncthreads();

    // per-channel epilogue: thread tid owns channel tid
    const int c = tid, hh = c >> 6, lane2 = tid & 63;
    float numc = lnum[0][c] + lnum[1][c] + lnum[2][c] + lnum[3][c];
    float denc = lden[0][hh] + lden[1][hh] + lden[2][hh] + lden[3][hh];
    float acc = bias[c] + numc / denc;

    // LayerNorm over 256 channels
    __shared__ float red[8];
    float wsum = acc, wsq = acc * acc;
    #pragma unroll
    for (int o = 1; o < 64; o <<= 1) {
        wsum += __shfl_xor(wsum, o, 64);
        wsq  += __shfl_xor(wsq,  o, 64);
    }
    if (lane2 == 0) { red[hh] = wsum; red[4 + hh] = wsq; }
    __syncthreads();
    float tot  = red[0] + red[1] + red[2] + red[3];
    float tot2 = red[4] + red[5] + red[6] + red[7];
    float mu = tot * (1.0f / 256.0f);
    float var = tot2 * (1.0f / 256.0f) - mu * mu;
    float rstd = rsqrtf(var + LN_EPS);

    float o = fmaxf((acc - mu) * rstd * g[c] + be[c], 0.0f);
    if (write32) out32[n * D + c] = o;
    else         out16[n * D + c] = (_Float16)o;
}

// ================= launch =================
extern "C" void kernel_launch(void* const* d_in, const int* in_sizes, int n_in,
                              void* d_out, int out_size, void* d_ws, size_t ws_size,
                              hipStream_t stream)
{
    const float* x  = (const float*)d_in[0];
    const int*   ei = (const int*)d_in[1];

    char* ws = (char*)d_ws;
    size_t off = 0;
    _Float16* h16   = (_Float16*)(ws + off); off += (size_t)N_NODES * D * 2;      // 10.24 MB
    _Float16* xl    = (_Float16*)(ws + off); off += (size_t)N_NODES * D * 2;      // 10.24 MB
    _Float16* xr    = (_Float16*)(ws + off); off += (size_t)N_NODES * D * 2;      // 10.24 MB
    _Float16* WtA   = (_Float16*)(ws + off); off += (size_t)8 * 65536 * 2;        // 1 MB
    int* rowptr     = (int*)(ws + off);      off += (size_t)(N_NODES + 32) * 4;
    int* cursor     = (int*)(ws + off);      off += (size_t)N_NODES * 4;
    int* csr_src    = (int*)(ws + off);      off += (size_t)EP * 4;

    // one-time per call
    convert_x_kernel<<<(N_NODES * D / 4 + 255) / 256, 256, 0, stream>>>(x, h16);
    csr_zero_kernel<<<(N_NODES + 255) / 256, 256, 0, stream>>>(cursor);          // cursor as deg
    csr_hist_kernel<<<(EP + 255) / 256, 256, 0, stream>>>(ei, cursor);
    csr_scan_kernel<<<1, 1024, 0, stream>>>(cursor, rowptr, cursor);
    csr_scatter_kernel<<<(EP + 255) / 256, 256, 0, stream>>>(ei, cursor, csr_src);

    WPtrs wp;
    for (int l = 0; l < 4; ++l) {
        wp.p[2 * l + 0] = (const float*)d_in[2 + 6 * l + 0];
        wp.p[2 * l + 1] = (const float*)d_in[2 + 6 * l + 1];
    }
    convw_all_kernel<<<dim3(4, 4, 8), 256, 0, stream>>>(wp, WtA);

    dim3 gemm_grid((N_NODES + BM - 1) / BM, 256 / BN, 2);   // (157, 2, 2)

    for (int l = 0; l < 4; ++l) {
        const float* att  = (const float*)d_in[2 + 6 * l + 2];
        const float* bias = (const float*)d_in[2 + 6 * l + 3];
        const float* g    = (const float*)d_in[2 + 6 * l + 4];
        const float* be   = (const float*)d_in[2 + 6 * l + 5];

        gemm_f16_kernel<<<gemm_grid, 256, 0, stream>>>(h16, WtA + (size_t)l * 131072,
                                                       xl, xr, N_NODES);
        gat_fused_kernel<<<N_NODES, 256, 0, stream>>>(xl, xr, rowptr, csr_src, att,
                                                      bias, g, be,
                                                      (float*)d_out, h16, (l == 3) ? 1 : 0);
    }
}

// Round 7
// 402.714 us; speedup vs baseline: 6.6843x; 1.0663x over previous
//
#include <hip/hip_runtime.h>
#include <math.h>

#define N_NODES 20000
#define E_EDGES 320000
#define EP (E_EDGES + N_NODES)   // 340000 edges incl. self-loops
#define D 256
#define NHEAD 4
#define CH 64
#define NEG_SLOPE 0.2f
#define LN_EPS 1e-5f

typedef _Float16 half8_t __attribute__((ext_vector_type(8)));
typedef _Float16 half4_t __attribute__((ext_vector_type(4)));
typedef _Float16 half2_t __attribute__((ext_vector_type(2)));
typedef float   float4_t __attribute__((ext_vector_type(4)));

// ========== one-time: convert x (fp32) -> f16, and zero the degree array ==========
__global__ __launch_bounds__(256)
void convert_x_kernel(const float* __restrict__ x, _Float16* __restrict__ h16,
                      int* __restrict__ deg)
{
    int i = blockIdx.x * 256 + threadIdx.x;          // one float4 per thread
    if (i < N_NODES) deg[i] = 0;
    if (i >= N_NODES * D / 4) return;
    float4 v = reinterpret_cast<const float4*>(x)[i];
    half4_t o;
    o.x = (_Float16)v.x; o.y = (_Float16)v.y; o.z = (_Float16)v.z; o.w = (_Float16)v.w;
    reinterpret_cast<half4_t*>(h16)[i] = o;
}

// ================= CSR build =================
__global__ __launch_bounds__(256)
void csr_hist_kernel(const int* __restrict__ ei, int* __restrict__ deg)
{
    int e = blockIdx.x * 256 + threadIdx.x;
    if (e >= EP) return;
    int dst = (e < E_EDGES) ? ei[E_EDGES + e] : (e - E_EDGES);
    atomicAdd(&deg[dst], 1);
}

__global__ __launch_bounds__(1024)
void csr_scan_kernel(const int* __restrict__ deg, int* __restrict__ rowptr,
                     int* __restrict__ cursor)
{
    __shared__ int wsum[16];
    __shared__ int carry;
    int t = threadIdx.x, lane = t & 63, w = t >> 6;
    if (t == 0) carry = 0;
    __syncthreads();
    for (int base = 0; base < N_NODES; base += 1024) {
        int i = base + t;
        int v = (i < N_NODES) ? deg[i] : 0;
        int x = v;
        #pragma unroll
        for (int o = 1; o < 64; o <<= 1) {
            int y = __shfl_up(x, o, 64);
            if (lane >= o) x += y;
        }
        if (lane == 63) wsum[w] = x;
        __syncthreads();
        if (t == 0) {
            int s = carry;
            #pragma unroll
            for (int k = 0; k < 16; ++k) { int tmp = wsum[k]; wsum[k] = s; s += tmp; }
            carry = s;
        }
        __syncthreads();
        int excl = wsum[w] + x - v;
        if (i < N_NODES) { rowptr[i] = excl; cursor[i] = excl; }
        __syncthreads();
    }
    if (t == 0) rowptr[N_NODES] = carry;
}

__global__ __launch_bounds__(256)
void csr_scatter_kernel(const int* __restrict__ ei, int* __restrict__ cursor,
                        int* __restrict__ csr_src)
{
    int e = blockIdx.x * 256 + threadIdx.x;
    if (e >= EP) return;
    int src, dst;
    if (e < E_EDGES) { src = ei[e]; dst = ei[E_EDGES + e]; }
    else             { src = dst = e - E_EDGES; }
    int pos = atomicAdd(&cursor[dst], 1);
    csr_src[pos] = src;
}

// ===== upfront: convert+transpose ALL 8 weight matrices to f16 [n][k] =====
struct WPtrs { const float* p[8]; };
// grid (4,4,8), block 256; z = layer*2 + side
__global__ __launch_bounds__(256)
void convw_all_kernel(WPtrs wp, _Float16* __restrict__ Wt_all)
{
    __shared__ float tile[64][65];
    const float* W = wp.p[blockIdx.z];
    _Float16* out = Wt_all + (size_t)blockIdx.z * 65536;
    int bx = blockIdx.x * 64, by = blockIdx.y * 64;
    int t = threadIdx.x;
    #pragma unroll
    for (int i = 0; i < 16; ++i) {
        int idx = t + i * 256;
        int kk = idx >> 6, nn = idx & 63;
        tile[kk][nn] = W[(by + kk) * 256 + bx + nn];
    }
    __syncthreads();
    #pragma unroll
    for (int i = 0; i < 16; ++i) {
        int idx = t + i * 256;
        int nn = idx >> 6, kk = idx & 63;
        out[(bx + nn) * 256 + by + kk] = (_Float16)tile[kk][nn];
    }
}

// ================= GEMM: X = A16 @ W (f16 MFMA, fp32 accum, f16 out) =================
// A16: [M][256] f16 row-major; Wt: [256][256] f16 laid out [n][k]
// grid (157, 2, 2): y = 128-col block, z = matrix. block 256 (4 waves).
// BM=128, BN=128, BK=32; wave w computes rows [32w,32w+32) x 128 cols.
#define BM 128
#define BN 128
#define BK 32
#define EPAD 136   // epilogue LDS row stride in f16 (272 B, 16B-aligned)
__global__ __launch_bounds__(256)
void gemm_f16_kernel(const _Float16* __restrict__ A16, const _Float16* __restrict__ Wt,
                     _Float16* __restrict__ X0, _Float16* __restrict__ X1, int nrows)
{
    const _Float16* W = Wt + blockIdx.z * 65536 + blockIdx.y * (BN * 256);
    _Float16* X = blockIdx.z ? X1 : X0;
    const int row0 = blockIdx.x * BM;
    const int col0 = blockIdx.y * BN;

    // union: staging tiles (20.5 KB) vs epilogue transpose buffer (34.8 KB)
    __shared__ char smem[4 * 32 * EPAD * 2];                       // 34816 B
    _Float16 (*As)[BK + 8] = reinterpret_cast<_Float16 (*)[BK + 8]>(smem);
    _Float16 (*Bs)[BK + 8] = reinterpret_cast<_Float16 (*)[BK + 8]>(smem + BM * (BK + 8) * 2);
    _Float16* ep = reinterpret_cast<_Float16*>(smem);

    const int tid  = threadIdx.x;
    const int wave = tid >> 6, lane = tid & 63;
    const int quad = lane >> 4, l16 = lane & 15;

    float4_t acc[2][8];
    #pragma unroll
    for (int i = 0; i < 2; ++i)
        #pragma unroll
        for (int j = 0; j < 8; ++j) acc[i][j] = (float4_t)0.0f;

    const int r_ld  = tid >> 2;            // 0..63 base row for staging
    const int kk_ld = (tid & 3) * 8;       // 0/8/16/24

    for (int k0 = 0; k0 < 256; k0 += BK) {
        // stage A: 128x32 f16 -> 2x 16B loads/thread
        #pragma unroll
        for (int i = 0; i < 2; ++i) {
            int r = r_ld + i * 64;
            int gr = row0 + r;
            half8_t v = (half8_t)(_Float16)0.0f;
            if (gr < nrows)
                v = *reinterpret_cast<const half8_t*>(A16 + gr * 256 + k0 + kk_ld);
            *reinterpret_cast<half8_t*>(&As[r][kk_ld]) = v;
        }
        // stage B: 128x32 f16 -> 2x 16B loads/thread
        #pragma unroll
        for (int i = 0; i < 2; ++i) {
            int r = r_ld + i * 64;
            half8_t v = *reinterpret_cast<const half8_t*>(W + r * 256 + k0 + kk_ld);
            *reinterpret_cast<half8_t*>(&Bs[r][kk_ld]) = v;
        }
        __syncthreads();

        half8_t af[2], bf[8];
        #pragma unroll
        for (int i = 0; i < 2; ++i)
            af[i] = *reinterpret_cast<const half8_t*>(&As[wave * 32 + i * 16 + l16][quad * 8]);
        #pragma unroll
        for (int j = 0; j < 8; ++j)
            bf[j] = *reinterpret_cast<const half8_t*>(&Bs[j * 16 + l16][quad * 8]);
        #pragma unroll
        for (int i = 0; i < 2; ++i)
            #pragma unroll
            for (int j = 0; j < 8; ++j)
                acc[i][j] = __builtin_amdgcn_mfma_f32_16x16x32_f16(af[i], bf[j], acc[i][j], 0, 0, 0);
        __syncthreads();
    }

    // ---- epilogue: per-wave LDS transpose -> coalesced half8 stores ----
    _Float16* epw = ep + wave * 32 * EPAD;
    #pragma unroll
    for (int i = 0; i < 2; ++i)
        #pragma unroll
        for (int j = 0; j < 8; ++j)
            #pragma unroll
            for (int r = 0; r < 4; ++r)
                epw[(i * 16 + quad * 4 + r) * EPAD + j * 16 + l16] = (_Float16)acc[i][j][r];
    // wave-internal dependency only (per-wave region): no barrier needed
    #pragma unroll
    for (int t = 0; t < 8; ++t) {
        int row = t * 4 + quad;                 // 0..31
        int gr = row0 + wave * 32 + row;
        half8_t v = *reinterpret_cast<const half8_t*>(&epw[row * EPAD + l16 * 8]);
        if (gr < nrows)
            *reinterpret_cast<half8_t*>(X + gr * 256 + col0 + l16 * 8) = v;
    }
}

// ===== fused GATv2 edge phase + LayerNorm + ReLU, one WAVE per node =====
// 4 nodes per block; waves fully independent (no LDS, no barriers).
// Lane l covers channels 4l..4l+3 (within head l>>4); per-head score
// reduction = 4 shuffle steps in 16-lane groups; den/num stay per-lane.
// Streaming softmax without max-subtraction (scores are O(+-5)).
__global__ __launch_bounds__(256)
void gat_fused_kernel(const _Float16* __restrict__ xl, const _Float16* __restrict__ xr,
                      const int* __restrict__ rowptr, const int* __restrict__ csr_src,
                      const float* __restrict__ att,
                      const float* __restrict__ bias, const float* __restrict__ g,
                      const float* __restrict__ be,
                      float* __restrict__ out32, _Float16* __restrict__ out16,
                      int write32)
{
    const int tid = threadIdx.x;
    const int w = tid >> 6, lane = tid & 63;
    const int n = blockIdx.x * 4 + w;
    const int start = rowptr[n], end = rowptr[n + 1];
    const int c0 = lane * 4;

    half2_t xr01, xr23, att01, att23;
    {
        half4_t xh = *reinterpret_cast<const half4_t*>(xr + n * D + c0);
        xr01.x = xh.x; xr01.y = xh.y; xr23.x = xh.z; xr23.y = xh.w;
        float4 av = *reinterpret_cast<const float4*>(att + c0);
        att01.x = (_Float16)av.x; att01.y = (_Float16)av.y;
        att23.x = (_Float16)av.z; att23.y = (_Float16)av.w;
    }
    const half2_t k02 = {(_Float16)NEG_SLOPE, (_Float16)NEG_SLOPE};

    float den = 0.0f;
    float4 num = make_float4(0.0f, 0.0f, 0.0f, 0.0f);

    int i = start;
    for (; i + 2 <= end; i += 2) {   // 2 edges in flight per wave
        int s0 = csr_src[i];
        int s1 = csr_src[i + 1];
        half4_t ha = *reinterpret_cast<const half4_t*>(xl + s0 * D + c0);
        half4_t hb = *reinterpret_cast<const half4_t*>(xl + s1 * D + c0);

        half2_t a01 = {ha.x, ha.y}, a23 = {ha.z, ha.w};
        half2_t b01 = {hb.x, hb.y}, b23 = {hb.z, hb.w};
        half2_t t0 = a01 + xr01, t1 = a23 + xr23;
        half2_t u0 = b01 + xr01, u1 = b23 + xr23;
        t0 = __builtin_elementwise_max(t0, t0 * k02);
        t1 = __builtin_elementwise_max(t1, t1 * k02);
        u0 = __builtin_elementwise_max(u0, u0 * k02);
        u1 = __builtin_elementwise_max(u1, u1 * k02);
        float va = __builtin_amdgcn_fdot2(t0, att01, 0.0f, false);
        va       = __builtin_amdgcn_fdot2(t1, att23, va,   false);
        float vb = __builtin_amdgcn_fdot2(u0, att01, 0.0f, false);
        vb       = __builtin_amdgcn_fdot2(u1, att23, vb,   false);
        #pragma unroll
        for (int o = 1; o < 16; o <<= 1) {
            va += __shfl_xor(va, o, 64);
            vb += __shfl_xor(vb, o, 64);
        }
        float pa = __expf(va), pb = __expf(vb);
        den += pa + pb;
        num.x = fmaf(pa, (float)ha.x, num.x); num.x = fmaf(pb, (float)hb.x, num.x);
        num.y = fmaf(pa, (float)ha.y, num.y); num.y = fmaf(pb, (float)hb.y, num.y);
        num.z = fmaf(pa, (float)ha.z, num.z); num.z = fmaf(pb, (float)hb.z, num.z);
        num.w = fmaf(pa, (float)ha.w, num.w); num.w = fmaf(pb, (float)hb.w, num.w);
    }
    if (i < end) {
        int s0 = csr_src[i];
        half4_t ha = *reinterpret_cast<const half4_t*>(xl + s0 * D + c0);
        half2_t a01 = {ha.x, ha.y}, a23 = {ha.z, ha.w};
        half2_t t0 = a01 + xr01, t1 = a23 + xr23;
        t0 = __builtin_elementwise_max(t0, t0 * k02);
        t1 = __builtin_elementwise_max(t1, t1 * k02);
        float va = __builtin_amdgcn_fdot2(t0, att01, 0.0f, false);
        va       = __builtin_amdgcn_fdot2(t1, att23, va,   false);
        #pragma unroll
        for (int o = 1; o < 16; o <<= 1) va += __shfl_xor(va, o, 64);
        float pa = __expf(va);
        den += pa;
        num.x = fmaf(pa, (float)ha.x, num.x);
        num.y = fmaf(pa, (float)ha.y, num.y);
        num.z = fmaf(pa, (float)ha.z, num.z);
        num.w = fmaf(pa, (float)ha.w, num.w);
    }

    // normalize + bias (den is already per-head correct for this lane)
    float inv_den = 1.0f / den;
    float4 bi = *reinterpret_cast<const float4*>(bias + c0);
    float a0 = fmaf(num.x, inv_den, bi.x);
    float a1 = fmaf(num.y, inv_den, bi.y);
    float a2 = fmaf(num.z, inv_den, bi.z);
    float a3 = fmaf(num.w, inv_den, bi.w);

    // LayerNorm over 256 channels: in-lane partial + 6-step butterfly
    float wsum = a0 + a1 + a2 + a3;
    float wsq  = a0 * a0 + a1 * a1 + a2 * a2 + a3 * a3;
    #pragma unroll
    for (int o = 1; o < 64; o <<= 1) {
        wsum += __shfl_xor(wsum, o, 64);
        wsq  += __shfl_xor(wsq,  o, 64);
    }
    float mu = wsum * (1.0f / 256.0f);
    float var = wsq * (1.0f / 256.0f) - mu * mu;
    float rstd = rsqrtf(var + LN_EPS);

    float4 gg = *reinterpret_cast<const float4*>(g + c0);
    float4 bb = *reinterpret_cast<const float4*>(be + c0);
    float o0 = fmaxf((a0 - mu) * rstd * gg.x + bb.x, 0.0f);
    float o1 = fmaxf((a1 - mu) * rstd * gg.y + bb.y, 0.0f);
    float o2 = fmaxf((a2 - mu) * rstd * gg.z + bb.z, 0.0f);
    float o3 = fmaxf((a3 - mu) * rstd * gg.w + bb.w, 0.0f);

    if (write32) {
        float4 o4 = make_float4(o0, o1, o2, o3);
        *reinterpret_cast<float4*>(out32 + n * D + c0) = o4;
    } else {
        half4_t o4;
        o4.x = (_Float16)o0; o4.y = (_Float16)o1; o4.z = (_Float16)o2; o4.w = (_Float16)o3;
        *reinterpret_cast<half4_t*>(out16 + n * D + c0) = o4;
    }
}

// ================= launch =================
extern "C" void kernel_launch(void* const* d_in, const int* in_sizes, int n_in,
                              void* d_out, int out_size, void* d_ws, size_t ws_size,
                              hipStream_t stream)
{
    const float* x  = (const float*)d_in[0];
    const int*   ei = (const int*)d_in[1];

    char* ws = (char*)d_ws;
    size_t off = 0;
    _Float16* h16   = (_Float16*)(ws + off); off += (size_t)N_NODES * D * 2;      // 10.24 MB
    _Float16* xl    = (_Float16*)(ws + off); off += (size_t)N_NODES * D * 2;      // 10.24 MB
    _Float16* xr    = (_Float16*)(ws + off); off += (size_t)N_NODES * D * 2;      // 10.24 MB
    _Float16* WtA   = (_Float16*)(ws + off); off += (size_t)8 * 65536 * 2;        // 1 MB
    int* rowptr     = (int*)(ws + off);      off += (size_t)(N_NODES + 32) * 4;
    int* cursor     = (int*)(ws + off);      off += (size_t)N_NODES * 4;
    int* csr_src    = (int*)(ws + off);      off += (size_t)EP * 4;

    // one-time per call
    convert_x_kernel<<<(N_NODES * D / 4 + 255) / 256, 256, 0, stream>>>(x, h16, cursor);
    csr_hist_kernel<<<(EP + 255) / 256, 256, 0, stream>>>(ei, cursor);
    csr_scan_kernel<<<1, 1024, 0, stream>>>(cursor, rowptr, cursor);
    csr_scatter_kernel<<<(EP + 255) / 256, 256, 0, stream>>>(ei, cursor, csr_src);

    WPtrs wp;
    for (int l = 0; l < 4; ++l) {
        wp.p[2 * l + 0] = (const float*)d_in[2 + 6 * l + 0];
        wp.p[2 * l + 1] = (const float*)d_in[2 + 6 * l + 1];
    }
    convw_all_kernel<<<dim3(4, 4, 8), 256, 0, stream>>>(wp, WtA);

    dim3 gemm_grid((N_NODES + BM - 1) / BM, 256 / BN, 2);   // (157, 2, 2)

    for (int l = 0; l < 4; ++l) {
        const float* att  = (const float*)d_in[2 + 6 * l + 2];
        const float* bias = (const float*)d_in[2 + 6 * l + 3];
        const float* g    = (const float*)d_in[2 + 6 * l + 4];
        const float* be   = (const float*)d_in[2 + 6 * l + 5];

        gemm_f16_kernel<<<gemm_grid, 256, 0, stream>>>(h16, WtA + (size_t)l * 131072,
                                                       xl, xr, N_NODES);
        gat_fused_kernel<<<N_NODES / 4, 256, 0, stream>>>(xl, xr, rowptr, csr_src, att,
                                                          bias, g, be,
                                                          (float*)d_out, h16, (l == 3) ? 1 : 0);
    }
}

// Round 8
// 386.256 us; speedup vs baseline: 6.9691x; 1.0426x over previous
//
#include <hip/hip_runtime.h>
#include <math.h>

#define N_NODES 20000
#define E_EDGES 320000
#define EP (E_EDGES + N_NODES)   // 340000 edges incl. self-loops
#define D 256
#define NHEAD 4
#define CH 64
#define NEG_SLOPE 0.2f
#define LN_EPS 1e-5f

typedef _Float16 half8_t __attribute__((ext_vector_type(8)));
typedef _Float16 half4_t __attribute__((ext_vector_type(4)));
typedef _Float16 half2_t __attribute__((ext_vector_type(2)));
typedef float   float4_t __attribute__((ext_vector_type(4)));

__device__ __forceinline__ void async_cp16(const void* g, void* l)
{
    __builtin_amdgcn_global_load_lds(
        (const __attribute__((address_space(1))) void*)g,
        (__attribute__((address_space(3))) void*)l, 16, 0, 0);
}

// ========== one-time: convert x (fp32) -> f16, and zero the degree array ==========
__global__ __launch_bounds__(256)
void convert_x_kernel(const float* __restrict__ x, _Float16* __restrict__ h16,
                      int* __restrict__ deg)
{
    int i = blockIdx.x * 256 + threadIdx.x;          // one float4 per thread
    if (i < N_NODES) deg[i] = 0;
    if (i >= N_NODES * D / 4) return;
    float4 v = reinterpret_cast<const float4*>(x)[i];
    half4_t o;
    o.x = (_Float16)v.x; o.y = (_Float16)v.y; o.z = (_Float16)v.z; o.w = (_Float16)v.w;
    reinterpret_cast<half4_t*>(h16)[i] = o;
}

// ================= CSR build =================
__global__ __launch_bounds__(256)
void csr_hist_kernel(const int* __restrict__ ei, int* __restrict__ deg)
{
    int e = blockIdx.x * 256 + threadIdx.x;
    if (e >= EP) return;
    int dst = (e < E_EDGES) ? ei[E_EDGES + e] : (e - E_EDGES);
    atomicAdd(&deg[dst], 1);
}

// single-pass block scan: thread t owns nodes [20t, 20t+20)
__global__ __launch_bounds__(1024)
void csr_scan_kernel(const int* __restrict__ deg, int* __restrict__ rowptr,
                     int* __restrict__ cursor)
{
    __shared__ int wsum[16];
    int t = threadIdx.x, lane = t & 63, w = t >> 6;
    int base = t * 20;
    int loc[20];
    int s = 0;
    #pragma unroll
    for (int k = 0; k < 20; ++k) {
        int idx = base + k;
        loc[k] = (idx < N_NODES) ? deg[idx] : 0;
        s += loc[k];
    }
    int x = s;
    #pragma unroll
    for (int o = 1; o < 64; o <<= 1) {
        int y = __shfl_up(x, o, 64);
        if (lane >= o) x += y;
    }
    if (lane == 63) wsum[w] = x;
    __syncthreads();
    if (t == 0) {
        int sacc = 0;
        #pragma unroll
        for (int k = 0; k < 16; ++k) { int tmp = wsum[k]; wsum[k] = sacc; sacc += tmp; }
        rowptr[N_NODES] = sacc;
    }
    __syncthreads();
    int excl = wsum[w] + x - s;
    #pragma unroll
    for (int k = 0; k < 20; ++k) {
        int idx = base + k;
        if (idx < N_NODES) { rowptr[idx] = excl; cursor[idx] = excl; }
        excl += loc[k];
    }
}

__global__ __launch_bounds__(256)
void csr_scatter_kernel(const int* __restrict__ ei, int* __restrict__ cursor,
                        int* __restrict__ csr_src)
{
    int e = blockIdx.x * 256 + threadIdx.x;
    if (e >= EP) return;
    int src, dst;
    if (e < E_EDGES) { src = ei[e]; dst = ei[E_EDGES + e]; }
    else             { src = dst = e - E_EDGES; }
    int pos = atomicAdd(&cursor[dst], 1);
    csr_src[pos] = src;
}

// ===== upfront: convert+transpose ALL 8 weight matrices to f16 [n][k] =====
struct WPtrs { const float* p[8]; };
// grid (4,4,8), block 256; z = layer*2 + side
__global__ __launch_bounds__(256)
void convw_all_kernel(WPtrs wp, _Float16* __restrict__ Wt_all)
{
    __shared__ float tile[64][65];
    const float* W = wp.p[blockIdx.z];
    _Float16* out = Wt_all + (size_t)blockIdx.z * 65536;
    int bx = blockIdx.x * 64, by = blockIdx.y * 64;
    int t = threadIdx.x;
    #pragma unroll
    for (int i = 0; i < 16; ++i) {
        int idx = t + i * 256;
        int kk = idx >> 6, nn = idx & 63;
        tile[kk][nn] = W[(by + kk) * 256 + bx + nn];
    }
    __syncthreads();
    #pragma unroll
    for (int i = 0; i < 16; ++i) {
        int idx = t + i * 256;
        int nn = idx >> 6, kk = idx & 63;
        out[(bx + nn) * 256 + by + kk] = (_Float16)tile[kk][nn];
    }
}

// ================= GEMM: X = A16 @ W (f16 MFMA, fp32 accum, f16 out) =================
// A16: [M][256] f16 row-major; Wt: [256][256] f16 laid out [n][k].
// grid (157, 2, 2): y = 128-col block, z = matrix. block 256 (4 waves).
// BM=128, BN=128, BK=64 (4 iters); staging via global_load_lds width=16
// into unpadded [128][64] f16 tiles (m97-style layout).
#define BM 128
#define BN 128
#define BK 64
#define EPAD 136   // epilogue LDS row stride in f16 (272 B, 16B-aligned)
__global__ __launch_bounds__(256)
void gemm_f16_kernel(const _Float16* __restrict__ A16, const _Float16* __restrict__ Wt,
                     _Float16* __restrict__ X0, _Float16* __restrict__ X1, int nrows)
{
    const _Float16* W = Wt + blockIdx.z * 65536 + blockIdx.y * (BN * 256);
    _Float16* X = blockIdx.z ? X1 : X0;
    const int row0 = blockIdx.x * BM;
    const int col0 = blockIdx.y * BN;

    // union: staging tiles (2 x 16 KB) vs epilogue transpose buffer (34.8 KB)
    __shared__ __align__(1024) char smem[4 * 32 * EPAD * 2];       // 34816 B
    _Float16 (*As)[BK] = reinterpret_cast<_Float16 (*)[BK]>(smem);
    _Float16 (*Bs)[BK] = reinterpret_cast<_Float16 (*)[BK]>(smem + BM * BK * 2);
    _Float16* As_flat = reinterpret_cast<_Float16*>(smem);
    _Float16* Bs_flat = reinterpret_cast<_Float16*>(smem + BM * BK * 2);
    _Float16* ep = reinterpret_cast<_Float16*>(smem);

    const int tid  = threadIdx.x;
    const int wave = tid >> 6, lane = tid & 63;
    const int quad = lane >> 4, l16 = lane & 15;

    float4_t acc[2][8];
    #pragma unroll
    for (int i = 0; i < 2; ++i)
        #pragma unroll
        for (int j = 0; j < 8; ++j) acc[i][j] = (float4_t)0.0f;

    // staging geometry: 16 instructions of 1 KB cover one 128x64 f16 tile;
    // instruction ia covers rows 8*ia..8*ia+7; lane l -> row 8*ia+(l>>3),
    // 16B chunk (l&7) within the 128 B row. Wave w issues ia = 4w..4w+3.
    const int r_in  = lane >> 3;          // 0..7
    const int c_in  = (lane & 7) * 8;     // f16 offset within row: 0..56

    #pragma unroll
    for (int k0 = 0; k0 < 256; k0 += BK) {
        #pragma unroll
        for (int j = 0; j < 4; ++j) {
            int ia  = wave * 4 + j;
            int row = ia * 8 + r_in;
            int gra = row0 + row;
            gra = (gra < nrows) ? gra : (nrows - 1);   // clamp; garbage rows never stored
            async_cp16(A16 + (size_t)gra * 256 + k0 + c_in, As_flat + ia * 512);
            async_cp16(W   + (size_t)row * 256 + k0 + c_in, Bs_flat + ia * 512);
        }
        __syncthreads();

        #pragma unroll
        for (int s = 0; s < 2; ++s) {
            half8_t af[2], bf[8];
            #pragma unroll
            for (int i = 0; i < 2; ++i)
                af[i] = *reinterpret_cast<const half8_t*>(&As[wave * 32 + i * 16 + l16][s * 32 + quad * 8]);
            #pragma unroll
            for (int j = 0; j < 8; ++j)
                bf[j] = *reinterpret_cast<const half8_t*>(&Bs[j * 16 + l16][s * 32 + quad * 8]);
            #pragma unroll
            for (int i = 0; i < 2; ++i)
                #pragma unroll
                for (int j = 0; j < 8; ++j)
                    acc[i][j] = __builtin_amdgcn_mfma_f32_16x16x32_f16(af[i], bf[j], acc[i][j], 0, 0, 0);
        }
        __syncthreads();
    }

    // ---- epilogue: per-wave LDS transpose -> coalesced half8 stores ----
    _Float16* epw = ep + wave * 32 * EPAD;
    #pragma unroll
    for (int i = 0; i < 2; ++i)
        #pragma unroll
        for (int j = 0; j < 8; ++j)
            #pragma unroll
            for (int r = 0; r < 4; ++r)
                epw[(i * 16 + quad * 4 + r) * EPAD + j * 16 + l16] = (_Float16)acc[i][j][r];
    // wave-internal dependency only (per-wave region): no barrier needed
    #pragma unroll
    for (int t = 0; t < 8; ++t) {
        int row = t * 4 + quad;                 // 0..31
        int gr = row0 + wave * 32 + row;
        half8_t v = *reinterpret_cast<const half8_t*>(&epw[row * EPAD + l16 * 8]);
        if (gr < nrows)
            *reinterpret_cast<half8_t*>(X + gr * 256 + col0 + l16 * 8) = v;
    }
}

// ===== fused GATv2 edge phase + LayerNorm + ReLU, one WAVE per node =====
// 4 nodes per block; waves fully independent (no LDS, no barriers).
// Lane l covers channels 4l..4l+3 (within head l>>4); per-head score
// reduction = 4 shuffle steps in 16-lane groups; den/num stay per-lane.
// Streaming softmax without max-subtraction (scores are O(+-5)).
__global__ __launch_bounds__(256)
void gat_fused_kernel(const _Float16* __restrict__ xl, const _Float16* __restrict__ xr,
                      const int* __restrict__ rowptr, const int* __restrict__ csr_src,
                      const float* __restrict__ att,
                      const float* __restrict__ bias, const float* __restrict__ g,
                      const float* __restrict__ be,
                      float* __restrict__ out32, _Float16* __restrict__ out16,
                      int write32)
{
    const int tid = threadIdx.x;
    const int w = tid >> 6, lane = tid & 63;
    const int n = blockIdx.x * 4 + w;
    const int start = rowptr[n], end = rowptr[n + 1];
    const int c0 = lane * 4;

    half2_t xr01, xr23, att01, att23;
    {
        half4_t xh = *reinterpret_cast<const half4_t*>(xr + n * D + c0);
        xr01.x = xh.x; xr01.y = xh.y; xr23.x = xh.z; xr23.y = xh.w;
        float4 av = *reinterpret_cast<const float4*>(att + c0);
        att01.x = (_Float16)av.x; att01.y = (_Float16)av.y;
        att23.x = (_Float16)av.z; att23.y = (_Float16)av.w;
    }
    const half2_t k02 = {(_Float16)NEG_SLOPE, (_Float16)NEG_SLOPE};

    float den = 0.0f;
    float4 num = make_float4(0.0f, 0.0f, 0.0f, 0.0f);

    int i = start;
    for (; i + 2 <= end; i += 2) {   // 2 edges in flight per wave
        int s0 = csr_src[i];
        int s1 = csr_src[i + 1];
        half4_t ha = *reinterpret_cast<const half4_t*>(xl + s0 * D + c0);
        half4_t hb = *reinterpret_cast<const half4_t*>(xl + s1 * D + c0);

        half2_t a01 = {ha.x, ha.y}, a23 = {ha.z, ha.w};
        half2_t b01 = {hb.x, hb.y}, b23 = {hb.z, hb.w};
        half2_t t0 = a01 + xr01, t1 = a23 + xr23;
        half2_t u0 = b01 + xr01, u1 = b23 + xr23;
        t0 = __builtin_elementwise_max(t0, t0 * k02);
        t1 = __builtin_elementwise_max(t1, t1 * k02);
        u0 = __builtin_elementwise_max(u0, u0 * k02);
        u1 = __builtin_elementwise_max(u1, u1 * k02);
        float va = __builtin_amdgcn_fdot2(t0, att01, 0.0f, false);
        va       = __builtin_amdgcn_fdot2(t1, att23, va,   false);
        float vb = __builtin_amdgcn_fdot2(u0, att01, 0.0f, false);
        vb       = __builtin_amdgcn_fdot2(u1, att23, vb,   false);
        #pragma unroll
        for (int o = 1; o < 16; o <<= 1) {
            va += __shfl_xor(va, o, 64);
            vb += __shfl_xor(vb, o, 64);
        }
        float pa = __expf(va), pb = __expf(vb);
        den += pa + pb;
        num.x = fmaf(pa, (float)ha.x, num.x); num.x = fmaf(pb, (float)hb.x, num.x);
        num.y = fmaf(pa, (float)ha.y, num.y); num.y = fmaf(pb, (float)hb.y, num.y);
        num.z = fmaf(pa, (float)ha.z, num.z); num.z = fmaf(pb, (float)hb.z, num.z);
        num.w = fmaf(pa, (float)ha.w, num.w); num.w = fmaf(pb, (float)hb.w, num.w);
    }
    if (i < end) {
        int s0 = csr_src[i];
        half4_t ha = *reinterpret_cast<const half4_t*>(xl + s0 * D + c0);
        half2_t a01 = {ha.x, ha.y}, a23 = {ha.z, ha.w};
        half2_t t0 = a01 + xr01, t1 = a23 + xr23;
        t0 = __builtin_elementwise_max(t0, t0 * k02);
        t1 = __builtin_elementwise_max(t1, t1 * k02);
        float va = __builtin_amdgcn_fdot2(t0, att01, 0.0f, false);
        va       = __builtin_amdgcn_fdot2(t1, att23, va,   false);
        #pragma unroll
        for (int o = 1; o < 16; o <<= 1) va += __shfl_xor(va, o, 64);
        float pa = __expf(va);
        den += pa;
        num.x = fmaf(pa, (float)ha.x, num.x);
        num.y = fmaf(pa, (float)ha.y, num.y);
        num.z = fmaf(pa, (float)ha.z, num.z);
        num.w = fmaf(pa, (float)ha.w, num.w);
    }

    // normalize + bias (den is already per-head correct for this lane)
    float inv_den = 1.0f / den;
    float4 bi = *reinterpret_cast<const float4*>(bias + c0);
    float a0 = fmaf(num.x, inv_den, bi.x);
    float a1 = fmaf(num.y, inv_den, bi.y);
    float a2 = fmaf(num.z, inv_den, bi.z);
    float a3 = fmaf(num.w, inv_den, bi.w);

    // LayerNorm over 256 channels: in-lane partial + 6-step butterfly
    float wsum = a0 + a1 + a2 + a3;
    float wsq  = a0 * a0 + a1 * a1 + a2 * a2 + a3 * a3;
    #pragma unroll
    for (int o = 1; o < 64; o <<= 1) {
        wsum += __shfl_xor(wsum, o, 64);
        wsq  += __shfl_xor(wsq,  o, 64);
    }
    float mu = wsum * (1.0f / 256.0f);
    float var = wsq * (1.0f / 256.0f) - mu * mu;
    float rstd = rsqrtf(var + LN_EPS);

    float4 gg = *reinterpret_cast<const float4*>(g + c0);
    float4 bb = *reinterpret_cast<const float4*>(be + c0);
    float o0 = fmaxf((a0 - mu) * rstd * gg.x + bb.x, 0.0f);
    float o1 = fmaxf((a1 - mu) * rstd * gg.y + bb.y, 0.0f);
    float o2 = fmaxf((a2 - mu) * rstd * gg.z + bb.z, 0.0f);
    float o3 = fmaxf((a3 - mu) * rstd * gg.w + bb.w, 0.0f);

    if (write32) {
        float4 o4 = make_float4(o0, o1, o2, o3);
        *reinterpret_cast<float4*>(out32 + n * D + c0) = o4;
    } else {
        half4_t o4;
        o4.x = (_Float16)o0; o4.y = (_Float16)o1; o4.z = (_Float16)o2; o4.w = (_Float16)o3;
        *reinterpret_cast<half4_t*>(out16 + n * D + c0) = o4;
    }
}

// ================= launch =================
extern "C" void kernel_launch(void* const* d_in, const int* in_sizes, int n_in,
                              void* d_out, int out_size, void* d_ws, size_t ws_size,
                              hipStream_t stream)
{
    const float* x  = (const float*)d_in[0];
    const int*   ei = (const int*)d_in[1];

    char* ws = (char*)d_ws;
    size_t off = 0;
    _Float16* h16   = (_Float16*)(ws + off); off += (size_t)N_NODES * D * 2;      // 10.24 MB
    _Float16* xl    = (_Float16*)(ws + off); off += (size_t)N_NODES * D * 2;      // 10.24 MB
    _Float16* xr    = (_Float16*)(ws + off); off += (size_t)N_NODES * D * 2;      // 10.24 MB
    _Float16* WtA   = (_Float16*)(ws + off); off += (size_t)8 * 65536 * 2;        // 1 MB
    int* rowptr     = (int*)(ws + off);      off += (size_t)(N_NODES + 32) * 4;
    int* cursor     = (int*)(ws + off);      off += (size_t)N_NODES * 4;
    int* csr_src    = (int*)(ws + off);      off += (size_t)EP * 4;

    // one-time per call
    convert_x_kernel<<<(N_NODES * D / 4 + 255) / 256, 256, 0, stream>>>(x, h16, cursor);
    csr_hist_kernel<<<(EP + 255) / 256, 256, 0, stream>>>(ei, cursor);
    csr_scan_kernel<<<1, 1024, 0, stream>>>(cursor, rowptr, cursor);
    csr_scatter_kernel<<<(EP + 255) / 256, 256, 0, stream>>>(ei, cursor, csr_src);

    WPtrs wp;
    for (int l = 0; l < 4; ++l) {
        wp.p[2 * l + 0] = (const float*)d_in[2 + 6 * l + 0];
        wp.p[2 * l + 1] = (const float*)d_in[2 + 6 * l + 1];
    }
    convw_all_kernel<<<dim3(4, 4, 8), 256, 0, stream>>>(wp, WtA);

    dim3 gemm_grid((N_NODES + BM - 1) / BM, 256 / BN, 2);   // (157, 2, 2)

    for (int l = 0; l < 4; ++l) {
        const float* att  = (const float*)d_in[2 + 6 * l + 2];
        const float* bias = (const float*)d_in[2 + 6 * l + 3];
        const float* g    = (const float*)d_in[2 + 6 * l + 4];
        const float* be   = (const float*)d_in[2 + 6 * l + 5];

        gemm_f16_kernel<<<gemm_grid, 256, 0, stream>>>(h16, WtA + (size_t)l * 131072,
                                                       xl, xr, N_NODES);
        gat_fused_kernel<<<N_NODES / 4, 256, 0, stream>>>(xl, xr, rowptr, csr_src, att,
                                                          bias, g, be,
                                                          (float*)d_out, h16, (l == 3) ? 1 : 0);
    }
}

// Round 9
// 355.486 us; speedup vs baseline: 7.5724x; 1.0866x over previous
//
#include <hip/hip_runtime.h>
#include <math.h>

#define N_NODES 20000
#define E_EDGES 320000
#define EP (E_EDGES + N_NODES)   // 340000 edges incl. self-loops
#define D 256
#define NHEAD 4
#define CH 64
#define NEG_SLOPE 0.2f
#define LN_EPS 1e-5f

typedef _Float16 half8_t __attribute__((ext_vector_type(8)));
typedef _Float16 half4_t __attribute__((ext_vector_type(4)));
typedef _Float16 half2_t __attribute__((ext_vector_type(2)));
typedef float   float4_t __attribute__((ext_vector_type(4)));

__device__ __forceinline__ void async_cp16(const void* g, void* l)
{
    __builtin_amdgcn_global_load_lds(
        (const __attribute__((address_space(1))) void*)g,
        (__attribute__((address_space(3))) void*)l, 16, 0, 0);
}

// ---- DPP row_ror reduction over 16-lane rows (pure VALU, no LDS pipe) ----
template<int CTRL>
__device__ __forceinline__ float dpp_add(float v) {
    int t = __builtin_amdgcn_update_dpp(0, __float_as_int(v), CTRL, 0xF, 0xF, true);
    return v + __int_as_float(t);
}
__device__ __forceinline__ float row_sum16(float v) {
    v = dpp_add<0x121>(v);   // ror 1
    v = dpp_add<0x122>(v);   // ror 2
    v = dpp_add<0x124>(v);   // ror 4
    v = dpp_add<0x128>(v);   // ror 8
    return v;
}

// ========== one-time: convert x (fp32) -> f16, and zero the degree array ==========
__global__ __launch_bounds__(256)
void convert_x_kernel(const float* __restrict__ x, _Float16* __restrict__ h16,
                      int* __restrict__ deg)
{
    int i = blockIdx.x * 256 + threadIdx.x;          // one float4 per thread
    if (i < N_NODES) deg[i] = 0;
    if (i >= N_NODES * D / 4) return;
    float4 v = reinterpret_cast<const float4*>(x)[i];
    half4_t o;
    o.x = (_Float16)v.x; o.y = (_Float16)v.y; o.z = (_Float16)v.z; o.w = (_Float16)v.w;
    reinterpret_cast<half4_t*>(h16)[i] = o;
}

// ================= CSR build =================
__global__ __launch_bounds__(256)
void csr_hist_kernel(const int* __restrict__ ei, int* __restrict__ deg)
{
    int e = blockIdx.x * 256 + threadIdx.x;
    if (e >= EP) return;
    int dst = (e < E_EDGES) ? ei[E_EDGES + e] : (e - E_EDGES);
    atomicAdd(&deg[dst], 1);
}

// single-pass block scan: thread t owns nodes [20t, 20t+20)
__global__ __launch_bounds__(1024)
void csr_scan_kernel(const int* __restrict__ deg, int* __restrict__ rowptr,
                     int* __restrict__ cursor)
{
    __shared__ int wsum[16];
    int t = threadIdx.x, lane = t & 63, w = t >> 6;
    int base = t * 20;
    int loc[20];
    int s = 0;
    #pragma unroll
    for (int k = 0; k < 20; ++k) {
        int idx = base + k;
        loc[k] = (idx < N_NODES) ? deg[idx] : 0;
        s += loc[k];
    }
    int x = s;
    #pragma unroll
    for (int o = 1; o < 64; o <<= 1) {
        int y = __shfl_up(x, o, 64);
        if (lane >= o) x += y;
    }
    if (lane == 63) wsum[w] = x;
    __syncthreads();
    if (t == 0) {
        int sacc = 0;
        #pragma unroll
        for (int k = 0; k < 16; ++k) { int tmp = wsum[k]; wsum[k] = sacc; sacc += tmp; }
        rowptr[N_NODES] = sacc;
    }
    __syncthreads();
    int excl = wsum[w] + x - s;
    #pragma unroll
    for (int k = 0; k < 20; ++k) {
        int idx = base + k;
        if (idx < N_NODES) { rowptr[idx] = excl; cursor[idx] = excl; }
        excl += loc[k];
    }
}

__global__ __launch_bounds__(256)
void csr_scatter_kernel(const int* __restrict__ ei, int* __restrict__ cursor,
                        int* __restrict__ csr_src)
{
    int e = blockIdx.x * 256 + threadIdx.x;
    if (e >= EP) return;
    int src, dst;
    if (e < E_EDGES) { src = ei[e]; dst = ei[E_EDGES + e]; }
    else             { src = dst = e - E_EDGES; }
    int pos = atomicAdd(&cursor[dst], 1);
    csr_src[pos] = src;
}

// ===== upfront: convert+transpose ALL 8 weight matrices to f16 [n][k] =====
struct WPtrs { const float* p[8]; };
// grid (4,4,8), block 256; z = layer*2 + side
__global__ __launch_bounds__(256)
void convw_all_kernel(WPtrs wp, _Float16* __restrict__ Wt_all)
{
    __shared__ float tile[64][65];
    const float* W = wp.p[blockIdx.z];
    _Float16* out = Wt_all + (size_t)blockIdx.z * 65536;
    int bx = blockIdx.x * 64, by = blockIdx.y * 64;
    int t = threadIdx.x;
    #pragma unroll
    for (int i = 0; i < 16; ++i) {
        int idx = t + i * 256;
        int kk = idx >> 6, nn = idx & 63;
        tile[kk][nn] = W[(by + kk) * 256 + bx + nn];
    }
    __syncthreads();
    #pragma unroll
    for (int i = 0; i < 16; ++i) {
        int idx = t + i * 256;
        int nn = idx >> 6, kk = idx & 63;
        out[(bx + nn) * 256 + by + kk] = (_Float16)tile[kk][nn];
    }
}

// ================= GEMM: X = A16 @ W (f16 MFMA, fp32 accum, f16 out) =================
// A16: [M][256] f16 row-major; Wt: [256][256] f16 laid out [n][k].
// grid (157, 2, 2): y = 128-col block, z = matrix. block 256 (4 waves).
// BM=128, BN=128, BK=64 (4 iters); staging via global_load_lds width=16
// into unpadded [128][64] f16 tiles (m97-style layout).
#define BM 128
#define BN 128
#define BK 64
#define EPAD 136   // epilogue LDS row stride in f16 (272 B, 16B-aligned)
__global__ __launch_bounds__(256)
void gemm_f16_kernel(const _Float16* __restrict__ A16, const _Float16* __restrict__ Wt,
                     _Float16* __restrict__ X0, _Float16* __restrict__ X1, int nrows)
{
    const _Float16* W = Wt + blockIdx.z * 65536 + blockIdx.y * (BN * 256);
    _Float16* X = blockIdx.z ? X1 : X0;
    const int row0 = blockIdx.x * BM;
    const int col0 = blockIdx.y * BN;

    // union: staging tiles (2 x 16 KB) vs epilogue transpose buffer (34.8 KB)
    __shared__ __align__(1024) char smem[4 * 32 * EPAD * 2];       // 34816 B
    _Float16 (*As)[BK] = reinterpret_cast<_Float16 (*)[BK]>(smem);
    _Float16 (*Bs)[BK] = reinterpret_cast<_Float16 (*)[BK]>(smem + BM * BK * 2);
    _Float16* As_flat = reinterpret_cast<_Float16*>(smem);
    _Float16* Bs_flat = reinterpret_cast<_Float16*>(smem + BM * BK * 2);
    _Float16* ep = reinterpret_cast<_Float16*>(smem);

    const int tid  = threadIdx.x;
    const int wave = tid >> 6, lane = tid & 63;
    const int quad = lane >> 4, l16 = lane & 15;

    float4_t acc[2][8];
    #pragma unroll
    for (int i = 0; i < 2; ++i)
        #pragma unroll
        for (int j = 0; j < 8; ++j) acc[i][j] = (float4_t)0.0f;

    // staging geometry: 16 instructions of 1 KB cover one 128x64 f16 tile;
    // instruction ia covers rows 8*ia..8*ia+7; lane l -> row 8*ia+(l>>3),
    // 16B chunk (l&7) within the 128 B row. Wave w issues ia = 4w..4w+3.
    const int r_in  = lane >> 3;          // 0..7
    const int c_in  = (lane & 7) * 8;     // f16 offset within row: 0..56

    #pragma unroll
    for (int k0 = 0; k0 < 256; k0 += BK) {
        #pragma unroll
        for (int j = 0; j < 4; ++j) {
            int ia  = wave * 4 + j;
            int row = ia * 8 + r_in;
            int gra = row0 + row;
            gra = (gra < nrows) ? gra : (nrows - 1);   // clamp; garbage rows never stored
            async_cp16(A16 + (size_t)gra * 256 + k0 + c_in, As_flat + ia * 512);
            async_cp16(W   + (size_t)row * 256 + k0 + c_in, Bs_flat + ia * 512);
        }
        __syncthreads();

        #pragma unroll
        for (int s = 0; s < 2; ++s) {
            half8_t af[2], bf[8];
            #pragma unroll
            for (int i = 0; i < 2; ++i)
                af[i] = *reinterpret_cast<const half8_t*>(&As[wave * 32 + i * 16 + l16][s * 32 + quad * 8]);
            #pragma unroll
            for (int j = 0; j < 8; ++j)
                bf[j] = *reinterpret_cast<const half8_t*>(&Bs[j * 16 + l16][s * 32 + quad * 8]);
            #pragma unroll
            for (int i = 0; i < 2; ++i)
                #pragma unroll
                for (int j = 0; j < 8; ++j)
                    acc[i][j] = __builtin_amdgcn_mfma_f32_16x16x32_f16(af[i], bf[j], acc[i][j], 0, 0, 0);
        }
        __syncthreads();
    }

    // ---- epilogue: per-wave LDS transpose -> coalesced half8 stores ----
    _Float16* epw = ep + wave * 32 * EPAD;
    #pragma unroll
    for (int i = 0; i < 2; ++i)
        #pragma unroll
        for (int j = 0; j < 8; ++j)
            #pragma unroll
            for (int r = 0; r < 4; ++r)
                epw[(i * 16 + quad * 4 + r) * EPAD + j * 16 + l16] = (_Float16)acc[i][j][r];
    // wave-internal dependency only (per-wave region): no barrier needed
    #pragma unroll
    for (int t = 0; t < 8; ++t) {
        int row = t * 4 + quad;                 // 0..31
        int gr = row0 + wave * 32 + row;
        half8_t v = *reinterpret_cast<const half8_t*>(&epw[row * EPAD + l16 * 8]);
        if (gr < nrows)
            *reinterpret_cast<half8_t*>(X + gr * 256 + col0 + l16 * 8) = v;
    }
}

// ===== fused GATv2 edge phase + LayerNorm + ReLU, one WAVE per node =====
// 4 nodes per block; waves fully independent (no LDS, no barriers).
// Lane l covers channels 4l..4l+3 (within head l>>4); per-head score
// reduction = 4 DPP row_ror adds (VALU-only). 4 edges in flight per wave.
// Streaming softmax without max-subtraction (scores are O(+-5)).
__global__ __launch_bounds__(256)
void gat_fused_kernel(const _Float16* __restrict__ xl, const _Float16* __restrict__ xr,
                      const int* __restrict__ rowptr, const int* __restrict__ csr_src,
                      const float* __restrict__ att,
                      const float* __restrict__ bias, const float* __restrict__ g,
                      const float* __restrict__ be,
                      float* __restrict__ out32, _Float16* __restrict__ out16,
                      int write32)
{
    const int tid = threadIdx.x;
    const int w = tid >> 6, lane = tid & 63;
    const int n = blockIdx.x * 4 + w;
    const int start = rowptr[n], end = rowptr[n + 1];
    const int c0 = lane * 4;

    half2_t xr01, xr23, att01, att23;
    {
        half4_t xh = *reinterpret_cast<const half4_t*>(xr + n * D + c0);
        xr01.x = xh.x; xr01.y = xh.y; xr23.x = xh.z; xr23.y = xh.w;
        float4 av = *reinterpret_cast<const float4*>(att + c0);
        att01.x = (_Float16)av.x; att01.y = (_Float16)av.y;
        att23.x = (_Float16)av.z; att23.y = (_Float16)av.w;
    }
    const half2_t k02 = {(_Float16)NEG_SLOPE, (_Float16)NEG_SLOPE};

    float den = 0.0f;
    float4 num = make_float4(0.0f, 0.0f, 0.0f, 0.0f);

    int i = start;
    for (; i + 4 <= end; i += 4) {   // 4 edges in flight per wave
        int s0 = csr_src[i], s1 = csr_src[i + 1], s2 = csr_src[i + 2], s3 = csr_src[i + 3];
        half4_t h0 = *reinterpret_cast<const half4_t*>(xl + s0 * D + c0);
        half4_t h1 = *reinterpret_cast<const half4_t*>(xl + s1 * D + c0);
        half4_t h2 = *reinterpret_cast<const half4_t*>(xl + s2 * D + c0);
        half4_t h3 = *reinterpret_cast<const half4_t*>(xl + s3 * D + c0);

        float p0, p1, p2, p3;
        {
            half2_t a01 = {h0.x, h0.y}, a23 = {h0.z, h0.w};
            half2_t t0 = a01 + xr01, t1 = a23 + xr23;
            t0 = __builtin_elementwise_max(t0, t0 * k02);
            t1 = __builtin_elementwise_max(t1, t1 * k02);
            float v = __builtin_amdgcn_fdot2(t0, att01, 0.0f, false);
            p0      = __builtin_amdgcn_fdot2(t1, att23, v,   false);
        }
        {
            half2_t a01 = {h1.x, h1.y}, a23 = {h1.z, h1.w};
            half2_t t0 = a01 + xr01, t1 = a23 + xr23;
            t0 = __builtin_elementwise_max(t0, t0 * k02);
            t1 = __builtin_elementwise_max(t1, t1 * k02);
            float v = __builtin_amdgcn_fdot2(t0, att01, 0.0f, false);
            p1      = __builtin_amdgcn_fdot2(t1, att23, v,   false);
        }
        {
            half2_t a01 = {h2.x, h2.y}, a23 = {h2.z, h2.w};
            half2_t t0 = a01 + xr01, t1 = a23 + xr23;
            t0 = __builtin_elementwise_max(t0, t0 * k02);
            t1 = __builtin_elementwise_max(t1, t1 * k02);
            float v = __builtin_amdgcn_fdot2(t0, att01, 0.0f, false);
            p2      = __builtin_amdgcn_fdot2(t1, att23, v,   false);
        }
        {
            half2_t a01 = {h3.x, h3.y}, a23 = {h3.z, h3.w};
            half2_t t0 = a01 + xr01, t1 = a23 + xr23;
            t0 = __builtin_elementwise_max(t0, t0 * k02);
            t1 = __builtin_elementwise_max(t1, t1 * k02);
            float v = __builtin_amdgcn_fdot2(t0, att01, 0.0f, false);
            p3      = __builtin_amdgcn_fdot2(t1, att23, v,   false);
        }
        // 4 interleaved VALU reduction chains (DPP row_ror within 16-lane rows)
        p0 = row_sum16(p0); p1 = row_sum16(p1);
        p2 = row_sum16(p2); p3 = row_sum16(p3);

        p0 = __expf(p0); p1 = __expf(p1); p2 = __expf(p2); p3 = __expf(p3);
        den += (p0 + p1) + (p2 + p3);
        num.x = fmaf(p0, (float)h0.x, num.x); num.x = fmaf(p1, (float)h1.x, num.x);
        num.x = fmaf(p2, (float)h2.x, num.x); num.x = fmaf(p3, (float)h3.x, num.x);
        num.y = fmaf(p0, (float)h0.y, num.y); num.y = fmaf(p1, (float)h1.y, num.y);
        num.y = fmaf(p2, (float)h2.y, num.y); num.y = fmaf(p3, (float)h3.y, num.y);
        num.z = fmaf(p0, (float)h0.z, num.z); num.z = fmaf(p1, (float)h1.z, num.z);
        num.z = fmaf(p2, (float)h2.z, num.z); num.z = fmaf(p3, (float)h3.z, num.z);
        num.w = fmaf(p0, (float)h0.w, num.w); num.w = fmaf(p1, (float)h1.w, num.w);
        num.w = fmaf(p2, (float)h2.w, num.w); num.w = fmaf(p3, (float)h3.w, num.w);
    }
    for (; i < end; ++i) {
        int s0 = csr_src[i];
        half4_t ha = *reinterpret_cast<const half4_t*>(xl + s0 * D + c0);
        half2_t a01 = {ha.x, ha.y}, a23 = {ha.z, ha.w};
        half2_t t0 = a01 + xr01, t1 = a23 + xr23;
        t0 = __builtin_elementwise_max(t0, t0 * k02);
        t1 = __builtin_elementwise_max(t1, t1 * k02);
        float va = __builtin_amdgcn_fdot2(t0, att01, 0.0f, false);
        va       = __builtin_amdgcn_fdot2(t1, att23, va,   false);
        va = row_sum16(va);
        float pa = __expf(va);
        den += pa;
        num.x = fmaf(pa, (float)ha.x, num.x);
        num.y = fmaf(pa, (float)ha.y, num.y);
        num.z = fmaf(pa, (float)ha.z, num.z);
        num.w = fmaf(pa, (float)ha.w, num.w);
    }

    // normalize + bias (den is already per-head correct for this lane)
    float inv_den = 1.0f / den;
    float4 bi = *reinterpret_cast<const float4*>(bias + c0);
    float a0 = fmaf(num.x, inv_den, bi.x);
    float a1 = fmaf(num.y, inv_den, bi.y);
    float a2 = fmaf(num.z, inv_den, bi.z);
    float a3 = fmaf(num.w, inv_den, bi.w);

    // LayerNorm over 256 channels: in-lane partial + 6-step butterfly
    float wsum = a0 + a1 + a2 + a3;
    float wsq  = a0 * a0 + a1 * a1 + a2 * a2 + a3 * a3;
    #pragma unroll
    for (int o = 1; o < 64; o <<= 1) {
        wsum += __shfl_xor(wsum, o, 64);
        wsq  += __shfl_xor(wsq,  o, 64);
    }
    float mu = wsum * (1.0f / 256.0f);
    float var = wsq * (1.0f / 256.0f) - mu * mu;
    float rstd = rsqrtf(var + LN_EPS);

    float4 gg = *reinterpret_cast<const float4*>(g + c0);
    float4 bb = *reinterpret_cast<const float4*>(be + c0);
    float o0 = fmaxf((a0 - mu) * rstd * gg.x + bb.x, 0.0f);
    float o1 = fmaxf((a1 - mu) * rstd * gg.y + bb.y, 0.0f);
    float o2 = fmaxf((a2 - mu) * rstd * gg.z + bb.z, 0.0f);
    float o3 = fmaxf((a3 - mu) * rstd * gg.w + bb.w, 0.0f);

    if (write32) {
        float4 o4 = make_float4(o0, o1, o2, o3);
        *reinterpret_cast<float4*>(out32 + n * D + c0) = o4;
    } else {
        half4_t o4;
        o4.x = (_Float16)o0; o4.y = (_Float16)o1; o4.z = (_Float16)o2; o4.w = (_Float16)o3;
        *reinterpret_cast<half4_t*>(out16 + n * D + c0) = o4;
    }
}

// ================= launch =================
extern "C" void kernel_launch(void* const* d_in, const int* in_sizes, int n_in,
                              void* d_out, int out_size, void* d_ws, size_t ws_size,
                              hipStream_t stream)
{
    const float* x  = (const float*)d_in[0];
    const int*   ei = (const int*)d_in[1];

    char* ws = (char*)d_ws;
    size_t off = 0;
    _Float16* h16   = (_Float16*)(ws + off); off += (size_t)N_NODES * D * 2;      // 10.24 MB
    _Float16* xl    = (_Float16*)(ws + off); off += (size_t)N_NODES * D * 2;      // 10.24 MB
    _Float16* xr    = (_Float16*)(ws + off); off += (size_t)N_NODES * D * 2;      // 10.24 MB
    _Float16* WtA   = (_Float16*)(ws + off); off += (size_t)8 * 65536 * 2;        // 1 MB
    int* rowptr     = (int*)(ws + off);      off += (size_t)(N_NODES + 32) * 4;
    int* cursor     = (int*)(ws + off);      off += (size_t)N_NODES * 4;
    int* csr_src    = (int*)(ws + off);      off += (size_t)EP * 4;

    // one-time per call
    convert_x_kernel<<<(N_NODES * D / 4 + 255) / 256, 256, 0, stream>>>(x, h16, cursor);
    csr_hist_kernel<<<(EP + 255) / 256, 256, 0, stream>>>(ei, cursor);
    csr_scan_kernel<<<1, 1024, 0, stream>>>(cursor, rowptr, cursor);
    csr_scatter_kernel<<<(EP + 255) / 256, 256, 0, stream>>>(ei, cursor, csr_src);

    WPtrs wp;
    for (int l = 0; l < 4; ++l) {
        wp.p[2 * l + 0] = (const float*)d_in[2 + 6 * l + 0];
        wp.p[2 * l + 1] = (const float*)d_in[2 + 6 * l + 1];
    }
    convw_all_kernel<<<dim3(4, 4, 8), 256, 0, stream>>>(wp, WtA);

    dim3 gemm_grid((N_NODES + BM - 1) / BM, 256 / BN, 2);   // (157, 2, 2)

    for (int l = 0; l < 4; ++l) {
        const float* att  = (const float*)d_in[2 + 6 * l + 2];
        const float* bias = (const float*)d_in[2 + 6 * l + 3];
        const float* g    = (const float*)d_in[2 + 6 * l + 4];
        const float* be   = (const float*)d_in[2 + 6 * l + 5];

        gemm_f16_kernel<<<gemm_grid, 256, 0, stream>>>(h16, WtA + (size_t)l * 131072,
                                                       xl, xr, N_NODES);
        gat_fused_kernel<<<N_NODES / 4, 256, 0, stream>>>(xl, xr, rowptr, csr_src, att,
                                                          bias, g, be,
                                                          (float*)d_out, h16, (l == 3) ? 1 : 0);
    }
}